// Round 1
// baseline (2412.138 us; speedup 1.0000x reference)
//
#include <hip/hip_runtime.h>
#include <math.h>

#define PDIM 18432      // B*L
#define LDIM 2304
#define BDIM 8
#define CDIM 256
#define DI   512
#define DS   16
#define HH   48         // dt_rank + 2*d_state

// ---------------- im2col (2x2 stride-2 patches -> [P,1024], k=(c,kh,kw)) ----
__global__ void k_im2col(const float* __restrict__ x, float* __restrict__ out) {
    int idx = blockIdx.x * 256 + threadIdx.x;       // over P*256
    int c = idx & 255;
    int p = idx >> 8;
    int b = p / LDIM;
    int l = p % LDIM;
    int i2 = l / 48, j2 = l % 48;
    const float* src = x + ((size_t)(b * CDIM + c) * 96 + 2 * i2) * 96 + 2 * j2;
    float4 v;
    v.x = src[0]; v.y = src[1]; v.z = src[96]; v.w = src[97];
    *reinterpret_cast<float4*>(out + (size_t)p * 1024 + c * 4) = v;
}

// ---------------- generic fp32 GEMM: C[M,N] = A[M,K] * B[N,K]^T -------------
// STORE_T==1: store C[p,n] to out[(b*256+n)*2304 + l]  (p = b*2304+l)
#define TM_ 128
#define TN_ 128
#define TK_ 16

template<int STORE_T>
__global__ __launch_bounds__(256)
void k_gemm(const float* __restrict__ A, int lda,
            const float* __restrict__ Bw, int ldb,
            float* __restrict__ C, int ldc,
            int M, int N, int K)
{
    __shared__ __align__(16) float As[TK_][TM_ + 4];
    __shared__ __align__(16) float Bs[TK_][TN_ + 4];
    int m0 = blockIdx.x * TM_;
    int n0 = blockIdx.y * TN_;
    int tid = threadIdx.x;
    int tx = tid & 15, ty = tid >> 4;
    float acc[8][8] = {};
    for (int k0 = 0; k0 < K; k0 += TK_) {
#pragma unroll
        for (int r = 0; r < 2; ++r) {
            int i = tid + 256 * r;            // 0..511
            int row = i >> 2;                 // 0..127
            int kc = (i & 3) << 2;            // 0,4,8,12
            float4 v = *reinterpret_cast<const float4*>(A + (size_t)(m0 + row) * lda + k0 + kc);
            As[kc + 0][row] = v.x; As[kc + 1][row] = v.y;
            As[kc + 2][row] = v.z; As[kc + 3][row] = v.w;
            int nrow = n0 + row;
            float4 w;
            if (nrow < N) w = *reinterpret_cast<const float4*>(Bw + (size_t)nrow * ldb + k0 + kc);
            else          w = make_float4(0.f, 0.f, 0.f, 0.f);
            Bs[kc + 0][row] = w.x; Bs[kc + 1][row] = w.y;
            Bs[kc + 2][row] = w.z; Bs[kc + 3][row] = w.w;
        }
        __syncthreads();
#pragma unroll
        for (int kk = 0; kk < TK_; ++kk) {
            float4 a0 = *reinterpret_cast<const float4*>(&As[kk][ty * 8]);
            float4 a1 = *reinterpret_cast<const float4*>(&As[kk][ty * 8 + 4]);
            float4 b0 = *reinterpret_cast<const float4*>(&Bs[kk][tx * 8]);
            float4 b1 = *reinterpret_cast<const float4*>(&Bs[kk][tx * 8 + 4]);
            float av[8] = {a0.x, a0.y, a0.z, a0.w, a1.x, a1.y, a1.z, a1.w};
            float bv[8] = {b0.x, b0.y, b0.z, b0.w, b1.x, b1.y, b1.z, b1.w};
#pragma unroll
            for (int i = 0; i < 8; ++i)
#pragma unroll
                for (int j = 0; j < 8; ++j)
                    acc[i][j] = fmaf(av[i], bv[j], acc[i][j]);
        }
        __syncthreads();
    }
#pragma unroll
    for (int i = 0; i < 8; ++i) {
        int m = m0 + ty * 8 + i;
#pragma unroll
        for (int j = 0; j < 8; ++j) {
            int n = n0 + tx * 8 + j;
            if (n < N) {
                if (STORE_T == 0) {
                    C[(size_t)m * ldc + n] = acc[i][j];
                } else {
                    int b = m / LDIM, l = m % LDIM;
                    C[((size_t)(b * CDIM + n)) * LDIM + l] = acc[i][j];
                }
            }
        }
    }
}

// ---------------- double LayerNorm, in place over [P,256] -------------------
__device__ __forceinline__ float block_sum256(float v, float* sm) {
#pragma unroll
    for (int m = 32; m; m >>= 1) v += __shfl_xor(v, m);
    __syncthreads();
    if ((threadIdx.x & 63) == 0) sm[threadIdx.x >> 6] = v;
    __syncthreads();
    return sm[0] + sm[1] + sm[2] + sm[3];
}

__global__ __launch_bounds__(256)
void k_ln2(float* __restrict__ xs,
           const float* __restrict__ g1, const float* __restrict__ b1,
           const float* __restrict__ g2, const float* __restrict__ b2)
{
    __shared__ float sm[4];
    int p = blockIdx.x;
    int c = threadIdx.x;
    float v = xs[(size_t)p * CDIM + c];
    // LN1
    float mu = block_sum256(v, sm) * (1.f / CDIM);
    float dv = v - mu;
    float var = block_sum256(dv * dv, sm) * (1.f / CDIM);
    float y = dv * rsqrtf(var + 1e-5f) * g1[c] + b1[c];
    // LN2
    float mu2 = block_sum256(y, sm) * (1.f / CDIM);
    float dy = y - mu2;
    float var2 = block_sum256(dy * dy, sm) * (1.f / CDIM);
    float y2 = dy * rsqrtf(var2 + 1e-5f) * g2[c] + b2[c];
    xs[(size_t)p * CDIM + c] = y2;
}

// ---------------- causal depthwise conv1d + SiLU ----------------------------
// xm stored interleaved in xz buffer: xm[p,d] = xz[p*1024 + d]
__global__ void k_conv1d(const float* __restrict__ xz, const float* __restrict__ wc,
                         const float* __restrict__ bc, float* __restrict__ xc)
{
    int idx = blockIdx.x * 256 + threadIdx.x;       // over P*512
    int d = idx & 511;
    int p = idx >> 9;
    int b = p / LDIM, l = p % LDIM;
    float4 w = *reinterpret_cast<const float4*>(wc + d * 4);
    const float* base = xz + (size_t)(b * LDIM) * 1024 + d;
    float acc = bc[d];
    if (l >= 3) acc = fmaf(base[(size_t)(l - 3) * 1024], w.x, acc);
    if (l >= 2) acc = fmaf(base[(size_t)(l - 2) * 1024], w.y, acc);
    if (l >= 1) acc = fmaf(base[(size_t)(l - 1) * 1024], w.z, acc);
    acc = fmaf(base[(size_t)l * 1024], w.w, acc);
    float sig = 1.f / (1.f + __expf(-acc));
    xc[(size_t)p * DI + d] = acc * sig;
}

// ---------------- dt = softplus(dbc[:, :16] @ w_dt^T + b_dt) ----------------
// writes into xm half of xz buffer (dead after conv1d)
__global__ void k_dt(const float* __restrict__ dbc, const float* __restrict__ wdt,
                     const float* __restrict__ bdt, float* __restrict__ dtout)
{
    int idx = blockIdx.x * 256 + threadIdx.x;       // over P*512
    int d = idx & 511;
    int p = idx >> 9;
    const float* r = dbc + (size_t)p * HH;
    const float* w = wdt + d * 16;
    float acc = bdt[d];
#pragma unroll
    for (int k = 0; k < 16; ++k) acc = fmaf(r[k], w[k], acc);
    float sp = fmaxf(acc, 0.f) + log1pf(__expf(-fabsf(acc)));
    dtout[(size_t)p * 1024 + d] = sp;
}

// ---------------- selective scan + gating, y written in place over xc -------
// 16 lanes per (b,d) group, lane s owns state s.
__global__ __launch_bounds__(256)
void k_scan(const float* __restrict__ xz,   // dt at [p*1024+d], z at [p*1024+512+d]
            const float* __restrict__ dbc,  // B at [p*48+16+s], C at [p*48+32+s]
            const float* __restrict__ Alog,
            const float* __restrict__ Dp,
            float* __restrict__ xc_y)       // in: xc [P,512]; out: y_final in place
{
    int g = blockIdx.x * 16 + (threadIdx.x >> 4);   // 0..4095 = (b,d)
    int s = threadIdx.x & 15;
    int b = g >> 9, d = g & 511;
    float A = -__expf(Alog[d * 16 + s]);
    float Dv = Dp[d];
    float h = 0.f;
    const float* xzb  = xz  + (size_t)(b * LDIM) * 1024;
    const float* dbcb = dbc + (size_t)(b * LDIM) * HH;
    float* xcb = xc_y + (size_t)(b * LDIM) * DI;
    for (int l = 0; l < LDIM; ++l) {
        float dt = xzb[(size_t)l * 1024 + d];
        float zv = xzb[(size_t)l * 1024 + 512 + d];
        float xv = xcb[(size_t)l * DI + d];
        float Bv = dbcb[l * HH + 16 + s];
        float Cv = dbcb[l * HH + 32 + s];
        float dA = __expf(dt * A);
        h = fmaf(dA, h, dt * Bv * xv);
        float pr = h * Cv;
        pr += __shfl_xor(pr, 1);
        pr += __shfl_xor(pr, 2);
        pr += __shfl_xor(pr, 4);
        pr += __shfl_xor(pr, 8);
        if (s == 0) {
            float y = pr + xv * Dv;
            float sig = 1.f / (1.f + __expf(-zv));
            xcb[(size_t)l * DI + d] = y * (zv * sig);
        }
    }
}

extern "C" void kernel_launch(void* const* d_in, const int* in_sizes, int n_in,
                              void* d_out, int out_size, void* d_ws, size_t ws_size,
                              hipStream_t stream) {
    const float* x      = (const float*)d_in[0];
    const float* w_down = (const float*)d_in[1];
    const float* g1     = (const float*)d_in[2];
    const float* b1     = (const float*)d_in[3];
    const float* g2     = (const float*)d_in[4];
    const float* b2     = (const float*)d_in[5];
    const float* w_in   = (const float*)d_in[6];
    const float* w_conv = (const float*)d_in[7];
    const float* b_conv = (const float*)d_in[8];
    const float* w_xprj = (const float*)d_in[9];
    const float* w_dt   = (const float*)d_in[10];
    const float* b_dt   = (const float*)d_in[11];
    const float* A_log  = (const float*)d_in[12];
    const float* Dp     = (const float*)d_in[13];
    const float* w_out  = (const float*)d_in[14];
    float* out = (float*)d_out;

    float* ws2 = (float*)d_ws;                       // [P,1024]: im2col -> xz (dt in xm half)
    float* ws3 = ws2 + (size_t)PDIM * 1024;          // [P,512]:  xc -> y (in place)

    // 1. im2col of 2x2/stride-2 patches
    k_im2col<<<PDIM * CDIM / 256, 256, 0, stream>>>(x, ws2);
    // 2. PatchMerging conv as GEMM -> xd in d_out  [P,256]
    k_gemm<0><<<dim3(PDIM / TM_, 2), 256, 0, stream>>>(ws2, 1024, w_down, 1024, out, 256,
                                                       PDIM, 256, 1024);
    // 3. double LayerNorm in place -> xs
    k_ln2<<<PDIM, 256, 0, stream>>>(out, g1, b1, g2, b2);
    // 4. xz = xs @ w_in^T  [P,1024] -> ws2
    k_gemm<0><<<dim3(PDIM / TM_, 8), 256, 0, stream>>>(out, 256, w_in, 256, ws2, 1024,
                                                       PDIM, 1024, 256);
    // 5. causal depthwise conv1d + SiLU -> xc in ws3
    k_conv1d<<<PDIM * DI / 256, 256, 0, stream>>>(ws2, w_conv, b_conv, ws3);
    // 6. dbc = xc @ w_xproj^T  [P,48] -> d_out (dead xs region)
    k_gemm<0><<<dim3(PDIM / TM_, 1), 256, 0, stream>>>(ws3, 512, w_xprj, 512, out, HH,
                                                       PDIM, HH, 512);
    // 7. dt = softplus(dbc[:, :16] @ w_dt^T + b_dt) -> xm half of ws2
    k_dt<<<PDIM * DI / 256, 256, 0, stream>>>(out, w_dt, b_dt, ws2);
    // 8. selective scan + gating, y in place over xc (ws3)
    k_scan<<<256, 256, 0, stream>>>(ws2, out, A_log, Dp, ws3);
    // 9. out = y @ w_out^T, stored transposed to [B,C,48,48]
    k_gemm<1><<<dim3(PDIM / TM_, 2), 256, 0, stream>>>(ws3, 512, w_out, 512, out, 0,
                                                       PDIM, 256, 512);
}

// Round 2
// 962.622 us; speedup vs baseline: 2.5058x; 2.5058x over previous
//
#include <hip/hip_runtime.h>
#include <math.h>

#define PDIM 18432      // B*L
#define LDIM 2304
#define BDIM 8
#define CDIM 256
#define DI   512
#define DS   16
#define HH   48         // dt_rank + 2*d_state

#define NSEG 24
#define SEGLEN 96       // LDIM / NSEG

// ---------------- im2col (2x2 stride-2 patches -> [P,1024], k=(c,kh,kw)) ----
__global__ void k_im2col(const float* __restrict__ x, float* __restrict__ out) {
    int idx = blockIdx.x * 256 + threadIdx.x;       // over P*256
    int c = idx & 255;
    int p = idx >> 8;
    int b = p / LDIM;
    int l = p % LDIM;
    int i2 = l / 48, j2 = l % 48;
    const float* src = x + ((size_t)(b * CDIM + c) * 96 + 2 * i2) * 96 + 2 * j2;
    float4 v;
    v.x = src[0]; v.y = src[1]; v.z = src[96]; v.w = src[97];
    *reinterpret_cast<float4*>(out + (size_t)p * 1024 + c * 4) = v;
}

// ---------------- generic fp32 GEMM: C[M,N] = A[M,K] * B[N,K]^T -------------
#define TM_ 128
#define TN_ 128
#define TK_ 16

template<int STORE_T>
__global__ __launch_bounds__(256)
void k_gemm(const float* __restrict__ A, int lda,
            const float* __restrict__ Bw, int ldb,
            float* __restrict__ C, int ldc,
            int M, int N, int K)
{
    __shared__ __align__(16) float As[TK_][TM_ + 4];
    __shared__ __align__(16) float Bs[TK_][TN_ + 4];
    int m0 = blockIdx.x * TM_;
    int n0 = blockIdx.y * TN_;
    int tid = threadIdx.x;
    int tx = tid & 15, ty = tid >> 4;
    float acc[8][8] = {};
    for (int k0 = 0; k0 < K; k0 += TK_) {
#pragma unroll
        for (int r = 0; r < 2; ++r) {
            int i = tid + 256 * r;            // 0..511
            int row = i >> 2;                 // 0..127
            int kc = (i & 3) << 2;            // 0,4,8,12
            float4 v = *reinterpret_cast<const float4*>(A + (size_t)(m0 + row) * lda + k0 + kc);
            As[kc + 0][row] = v.x; As[kc + 1][row] = v.y;
            As[kc + 2][row] = v.z; As[kc + 3][row] = v.w;
            int nrow = n0 + row;
            float4 w;
            if (nrow < N) w = *reinterpret_cast<const float4*>(Bw + (size_t)nrow * ldb + k0 + kc);
            else          w = make_float4(0.f, 0.f, 0.f, 0.f);
            Bs[kc + 0][row] = w.x; Bs[kc + 1][row] = w.y;
            Bs[kc + 2][row] = w.z; Bs[kc + 3][row] = w.w;
        }
        __syncthreads();
#pragma unroll
        for (int kk = 0; kk < TK_; ++kk) {
            float4 a0 = *reinterpret_cast<const float4*>(&As[kk][ty * 8]);
            float4 a1 = *reinterpret_cast<const float4*>(&As[kk][ty * 8 + 4]);
            float4 b0 = *reinterpret_cast<const float4*>(&Bs[kk][tx * 8]);
            float4 b1 = *reinterpret_cast<const float4*>(&Bs[kk][tx * 8 + 4]);
            float av[8] = {a0.x, a0.y, a0.z, a0.w, a1.x, a1.y, a1.z, a1.w};
            float bv[8] = {b0.x, b0.y, b0.z, b0.w, b1.x, b1.y, b1.z, b1.w};
#pragma unroll
            for (int i = 0; i < 8; ++i)
#pragma unroll
                for (int j = 0; j < 8; ++j)
                    acc[i][j] = fmaf(av[i], bv[j], acc[i][j]);
        }
        __syncthreads();
    }
#pragma unroll
    for (int i = 0; i < 8; ++i) {
        int m = m0 + ty * 8 + i;
#pragma unroll
        for (int j = 0; j < 8; ++j) {
            int n = n0 + tx * 8 + j;
            if (n < N) {
                if (STORE_T == 0) {
                    C[(size_t)m * ldc + n] = acc[i][j];
                } else {
                    int b = m / LDIM, l = m % LDIM;
                    C[((size_t)(b * CDIM + n)) * LDIM + l] = acc[i][j];
                }
            }
        }
    }
}

// ---------------- double LayerNorm, in place over [P,256] -------------------
__device__ __forceinline__ float block_sum256(float v, float* sm) {
#pragma unroll
    for (int m = 32; m; m >>= 1) v += __shfl_xor(v, m);
    __syncthreads();
    if ((threadIdx.x & 63) == 0) sm[threadIdx.x >> 6] = v;
    __syncthreads();
    return sm[0] + sm[1] + sm[2] + sm[3];
}

__global__ __launch_bounds__(256)
void k_ln2(float* __restrict__ xs,
           const float* __restrict__ g1, const float* __restrict__ b1,
           const float* __restrict__ g2, const float* __restrict__ b2)
{
    __shared__ float sm[4];
    int p = blockIdx.x;
    int c = threadIdx.x;
    float v = xs[(size_t)p * CDIM + c];
    float mu = block_sum256(v, sm) * (1.f / CDIM);
    float dv = v - mu;
    float var = block_sum256(dv * dv, sm) * (1.f / CDIM);
    float y = dv * rsqrtf(var + 1e-5f) * g1[c] + b1[c];
    float mu2 = block_sum256(y, sm) * (1.f / CDIM);
    float dy = y - mu2;
    float var2 = block_sum256(dy * dy, sm) * (1.f / CDIM);
    float y2 = dy * rsqrtf(var2 + 1e-5f) * g2[c] + b2[c];
    xs[(size_t)p * CDIM + c] = y2;
}

// ---------------- causal depthwise conv1d + SiLU ----------------------------
__global__ void k_conv1d(const float* __restrict__ xz, const float* __restrict__ wc,
                         const float* __restrict__ bc, float* __restrict__ xc)
{
    int idx = blockIdx.x * 256 + threadIdx.x;       // over P*512
    int d = idx & 511;
    int p = idx >> 9;
    int b = p / LDIM, l = p % LDIM;
    float4 w = *reinterpret_cast<const float4*>(wc + d * 4);
    const float* base = xz + (size_t)(b * LDIM) * 1024 + d;
    float acc = bc[d];
    if (l >= 3) acc = fmaf(base[(size_t)(l - 3) * 1024], w.x, acc);
    if (l >= 2) acc = fmaf(base[(size_t)(l - 2) * 1024], w.y, acc);
    if (l >= 1) acc = fmaf(base[(size_t)(l - 1) * 1024], w.z, acc);
    acc = fmaf(base[(size_t)l * 1024], w.w, acc);
    float sig = 1.f / (1.f + __expf(-acc));
    xc[(size_t)p * DI + d] = acc * sig;
}

// ---------------- dt = softplus(dbc[:, :16] @ w_dt^T + b_dt) ----------------
__global__ void k_dt(const float* __restrict__ dbc, const float* __restrict__ wdt,
                     const float* __restrict__ bdt, float* __restrict__ dtout)
{
    int idx = blockIdx.x * 256 + threadIdx.x;       // over P*512
    int d = idx & 511;
    int p = idx >> 9;
    const float* r = dbc + (size_t)p * HH;
    const float* w = wdt + d * 16;
    float acc = bdt[d];
#pragma unroll
    for (int k = 0; k < 16; ++k) acc = fmaf(r[k], w[k], acc);
    float sp = fmaxf(acc, 0.f) + log1pf(__expf(-fabsf(acc)));
    dtout[(size_t)p * 1024 + d] = sp;
}

// ---------------- segmented selective scan ----------------------------------
// thread = (b, seg, d), 16 states in registers.
// Phase 1: per-segment a_prod = prod(dA), h_out from h_init=0.
__global__ __launch_bounds__(256)
void k_scan_p1(const float* __restrict__ xz,   // dt at [p*1024+d]
               const float* __restrict__ dbc,  // B at [p*48+16+s]
               const float* __restrict__ Alog,
               const float* __restrict__ xc,
               float* __restrict__ aprod, float* __restrict__ hout)
{
    int t = blockIdx.x * 256 + threadIdx.x;        // G*NSEG = 98304
    int d = t & 511;
    int rest = t >> 9;                             // b*NSEG + seg
    int b = rest / NSEG, seg = rest % NSEG;
    int l0 = seg * SEGLEN;
    float A[16], h[16], ap[16];
#pragma unroll
    for (int i = 0; i < 4; ++i) {
        float4 v = *reinterpret_cast<const float4*>(Alog + d * 16 + i * 4);
        A[4*i+0] = -__expf(v.x); A[4*i+1] = -__expf(v.y);
        A[4*i+2] = -__expf(v.z); A[4*i+3] = -__expf(v.w);
    }
#pragma unroll
    for (int s = 0; s < 16; ++s) { h[s] = 0.f; ap[s] = 1.f; }
    const float* dtp  = xz  + (size_t)(b * LDIM) * 1024;
    const float* xcp  = xc  + (size_t)(b * LDIM) * DI;
    const float* dbcb = dbc + (size_t)(b * LDIM) * HH;
    for (int i = 0; i < SEGLEN; ++i) {
        int l = l0 + i;
        float dt = dtp[(size_t)l * 1024 + d];
        float xv = xcp[(size_t)l * DI + d];
        float4 B0 = *reinterpret_cast<const float4*>(dbcb + l * HH + 16);
        float4 B1 = *reinterpret_cast<const float4*>(dbcb + l * HH + 20);
        float4 B2 = *reinterpret_cast<const float4*>(dbcb + l * HH + 24);
        float4 B3 = *reinterpret_cast<const float4*>(dbcb + l * HH + 28);
        float Bv[16] = {B0.x,B0.y,B0.z,B0.w, B1.x,B1.y,B1.z,B1.w,
                        B2.x,B2.y,B2.z,B2.w, B3.x,B3.y,B3.z,B3.w};
        float dtx = dt * xv;
#pragma unroll
        for (int s = 0; s < 16; ++s) {
            float dA = __expf(dt * A[s]);
            h[s] = fmaf(dA, h[s], dtx * Bv[s]);
            ap[s] *= dA;
        }
    }
    size_t base = ((size_t)((b * DI + d) * NSEG) + seg) * 16;
    float4* apo = reinterpret_cast<float4*>(aprod + base);
    float4* hoo = reinterpret_cast<float4*>(hout + base);
#pragma unroll
    for (int i = 0; i < 4; ++i) {
        apo[i] = make_float4(ap[4*i], ap[4*i+1], ap[4*i+2], ap[4*i+3]);
        hoo[i] = make_float4(h[4*i],  h[4*i+1],  h[4*i+2],  h[4*i+3]);
    }
}

// Phase 2: sequential combine across segments; h_init written over aprod.
__global__ __launch_bounds__(256)
void k_scan_p2(float* __restrict__ aprod, const float* __restrict__ hout)
{
    int t = blockIdx.x * 256 + threadIdx.x;        // G*16 = 65536
    int s = t & 15;
    int g = t >> 4;                                // b*512 + d
    float h = 0.f;
    for (int seg = 0; seg < NSEG; ++seg) {
        size_t idx = ((size_t)g * NSEG + seg) * 16 + s;
        float a  = aprod[idx];
        float ho = hout[idx];
        aprod[idx] = h;                            // h_init for this segment
        h = fmaf(a, h, ho);
    }
}

// Phase 3: re-run segment from h_init, produce y + D-skip + SiLU gating.
__global__ __launch_bounds__(256)
void k_scan_p3(const float* __restrict__ xz,   // dt at [p*1024+d], z at [p*1024+512+d]
               const float* __restrict__ dbc,  // B at +16, C at +32
               const float* __restrict__ Alog,
               const float* __restrict__ Dp,
               const float* __restrict__ hinit,
               float* __restrict__ xc_y)       // in: xc; out: y in place
{
    int t = blockIdx.x * 256 + threadIdx.x;
    int d = t & 511;
    int rest = t >> 9;
    int b = rest / NSEG, seg = rest % NSEG;
    int l0 = seg * SEGLEN;
    float A[16], h[16];
#pragma unroll
    for (int i = 0; i < 4; ++i) {
        float4 v = *reinterpret_cast<const float4*>(Alog + d * 16 + i * 4);
        A[4*i+0] = -__expf(v.x); A[4*i+1] = -__expf(v.y);
        A[4*i+2] = -__expf(v.z); A[4*i+3] = -__expf(v.w);
    }
    size_t base = ((size_t)((b * DI + d) * NSEG) + seg) * 16;
#pragma unroll
    for (int i = 0; i < 4; ++i) {
        float4 v = *reinterpret_cast<const float4*>(hinit + base + 4 * i);
        h[4*i+0] = v.x; h[4*i+1] = v.y; h[4*i+2] = v.z; h[4*i+3] = v.w;
    }
    float Dv = Dp[d];
    const float* dtp  = xz  + (size_t)(b * LDIM) * 1024;
    const float* dbcb = dbc + (size_t)(b * LDIM) * HH;
    float* xcb = xc_y + (size_t)(b * LDIM) * DI;
    for (int i = 0; i < SEGLEN; ++i) {
        int l = l0 + i;
        float dt = dtp[(size_t)l * 1024 + d];
        float zv = dtp[(size_t)l * 1024 + 512 + d];
        float xv = xcb[(size_t)l * DI + d];
        float4 B0 = *reinterpret_cast<const float4*>(dbcb + l * HH + 16);
        float4 B1 = *reinterpret_cast<const float4*>(dbcb + l * HH + 20);
        float4 B2 = *reinterpret_cast<const float4*>(dbcb + l * HH + 24);
        float4 B3 = *reinterpret_cast<const float4*>(dbcb + l * HH + 28);
        float4 C0 = *reinterpret_cast<const float4*>(dbcb + l * HH + 32);
        float4 C1 = *reinterpret_cast<const float4*>(dbcb + l * HH + 36);
        float4 C2 = *reinterpret_cast<const float4*>(dbcb + l * HH + 40);
        float4 C3 = *reinterpret_cast<const float4*>(dbcb + l * HH + 44);
        float Bv[16] = {B0.x,B0.y,B0.z,B0.w, B1.x,B1.y,B1.z,B1.w,
                        B2.x,B2.y,B2.z,B2.w, B3.x,B3.y,B3.z,B3.w};
        float Cv[16] = {C0.x,C0.y,C0.z,C0.w, C1.x,C1.y,C1.z,C1.w,
                        C2.x,C2.y,C2.z,C2.w, C3.x,C3.y,C3.z,C3.w};
        float dtx = dt * xv;
        float y = 0.f;
#pragma unroll
        for (int s = 0; s < 16; ++s) {
            float dA = __expf(dt * A[s]);
            h[s] = fmaf(dA, h[s], dtx * Bv[s]);
            y = fmaf(h[s], Cv[s], y);
        }
        y = fmaf(xv, Dv, y);
        float sig = 1.f / (1.f + __expf(-zv));
        xcb[(size_t)l * DI + d] = y * (zv * sig);
    }
}

extern "C" void kernel_launch(void* const* d_in, const int* in_sizes, int n_in,
                              void* d_out, int out_size, void* d_ws, size_t ws_size,
                              hipStream_t stream) {
    const float* x      = (const float*)d_in[0];
    const float* w_down = (const float*)d_in[1];
    const float* g1     = (const float*)d_in[2];
    const float* b1     = (const float*)d_in[3];
    const float* g2     = (const float*)d_in[4];
    const float* b2     = (const float*)d_in[5];
    const float* w_in   = (const float*)d_in[6];
    const float* w_conv = (const float*)d_in[7];
    const float* b_conv = (const float*)d_in[8];
    const float* w_xprj = (const float*)d_in[9];
    const float* w_dt   = (const float*)d_in[10];
    const float* b_dt   = (const float*)d_in[11];
    const float* A_log  = (const float*)d_in[12];
    const float* Dp     = (const float*)d_in[13];
    const float* w_out  = (const float*)d_in[14];
    float* out = (float*)d_out;

    float* ws2 = (float*)d_ws;                       // [P,1024]: im2col -> xz (dt in xm half)
    float* ws3 = ws2 + (size_t)PDIM * 1024;          // [P,512]:  xc -> y (in place)
    // segment scratch lives in the dead tail of d_out (dbc uses first P*48
    // floats; total d_out = P*256 floats; final GEMM rewrites all of it)
    float* aprod = out + (size_t)PDIM * HH;                      // 1572864 floats
    float* hout  = aprod + (size_t)BDIM * DI * NSEG * 16;        // 1572864 floats

    // 1. im2col of 2x2/stride-2 patches
    k_im2col<<<PDIM * CDIM / 256, 256, 0, stream>>>(x, ws2);
    // 2. PatchMerging conv as GEMM -> xd in d_out  [P,256]
    k_gemm<0><<<dim3(PDIM / TM_, 2), 256, 0, stream>>>(ws2, 1024, w_down, 1024, out, 256,
                                                       PDIM, 256, 1024);
    // 3. double LayerNorm in place -> xs
    k_ln2<<<PDIM, 256, 0, stream>>>(out, g1, b1, g2, b2);
    // 4. xz = xs @ w_in^T  [P,1024] -> ws2
    k_gemm<0><<<dim3(PDIM / TM_, 8), 256, 0, stream>>>(out, 256, w_in, 256, ws2, 1024,
                                                       PDIM, 1024, 256);
    // 5. causal depthwise conv1d + SiLU -> xc in ws3
    k_conv1d<<<PDIM * DI / 256, 256, 0, stream>>>(ws2, w_conv, b_conv, ws3);
    // 6. dbc = xc @ w_xproj^T  [P,48] -> d_out (dead xs region)
    k_gemm<0><<<dim3(PDIM / TM_, 1), 256, 0, stream>>>(ws3, 512, w_xprj, 512, out, HH,
                                                       PDIM, HH, 512);
    // 7. dt = softplus(dbc[:, :16] @ w_dt^T + b_dt) -> xm half of ws2
    k_dt<<<PDIM * DI / 256, 256, 0, stream>>>(out, w_dt, b_dt, ws2);
    // 8. segmented selective scan + gating, y in place over xc (ws3)
    k_scan_p1<<<BDIM * NSEG * DI / 256, 256, 0, stream>>>(ws2, out, A_log, ws3, aprod, hout);
    k_scan_p2<<<BDIM * DI * 16 / 256, 256, 0, stream>>>(aprod, hout);
    k_scan_p3<<<BDIM * NSEG * DI / 256, 256, 0, stream>>>(ws2, out, A_log, Dp, aprod, ws3);
    // 9. out = y @ w_out^T, stored transposed to [B,C,48,48]
    k_gemm<1><<<dim3(PDIM / TM_, 2), 256, 0, stream>>>(ws3, 512, w_out, 512, out, 0,
                                                       PDIM, 256, 512);
}

// Round 3
// 489.177 us; speedup vs baseline: 4.9310x; 1.9678x over previous
//
#include <hip/hip_runtime.h>
#include <math.h>

#define PDIM 18432      // B*L
#define LDIM 2304
#define BDIM 8
#define CDIM 256
#define DI   512
#define DS   16
#define HH   48         // dt_rank + 2*d_state

#define NSEG 24
#define SEGLEN 96       // LDIM / NSEG

typedef short short8v __attribute__((ext_vector_type(8)));
typedef float f32x4 __attribute__((ext_vector_type(4)));

__device__ __forceinline__ unsigned short f2bf(float f) {
    unsigned u = __float_as_uint(f);
    unsigned r = (u + 0x7fff + ((u >> 16) & 1)) >> 16;
    return (unsigned short)r;
}
__device__ __forceinline__ float b2f(unsigned short u) {
    return __uint_as_float(((unsigned)u) << 16);
}

// ---------------- fp32 -> bf16 cast (weights) -------------------------------
__global__ void k_cast(const float* __restrict__ src, unsigned short* __restrict__ dst, int n) {
    int i = blockIdx.x * 256 + threadIdx.x;
    if (i < n) dst[i] = f2bf(src[i]);
}

// ---------------- im2col -> bf16 [P,1024], k=(c,kh,kw) ----------------------
__global__ void k_im2col(const float* __restrict__ x, unsigned short* __restrict__ out) {
    int idx = blockIdx.x * 256 + threadIdx.x;       // over P*256
    int c = idx & 255;
    int p = idx >> 8;
    int b = p / LDIM;
    int l = p % LDIM;
    int i2 = l / 48, j2 = l % 48;
    const float* src = x + ((size_t)(b * CDIM + c) * 96 + 2 * i2) * 96 + 2 * j2;
    ushort4 v;
    v.x = f2bf(src[0]); v.y = f2bf(src[1]); v.z = f2bf(src[96]); v.w = f2bf(src[97]);
    *reinterpret_cast<ushort4*>(out + (size_t)p * 1024 + c * 4) = v;
}

// ---------------- bf16 MFMA GEMM: C[M,N] = A[M,K] * B[N,K]^T ----------------
// 128x128 tile, BK=64, 4 waves each owning 64x64 (4x4 frags of 16x16x32).
// STORE_MODE 0: fp32 row-major; 1: fp32 transposed [(b*256+n)*2304+l]; 2: bf16 row-major
template<int STORE_MODE>
__global__ __launch_bounds__(256)
void k_gemm_mfma(const unsigned short* __restrict__ A, int lda,
                 const unsigned short* __restrict__ Bw, int ldb,
                 void* __restrict__ Cout, int ldc,
                 int N, int K)
{
    __shared__ __align__(16) unsigned short Asm[128 * 64];
    __shared__ __align__(16) unsigned short Bsm[128 * 64];
    int m0 = blockIdx.x * 128;
    int n0 = blockIdx.y * 128;
    int tid = threadIdx.x;
    int lane = tid & 63;
    int wid = tid >> 6;
    int wr = wid >> 1, wc = wid & 1;

    f32x4 acc[4][4];
#pragma unroll
    for (int m = 0; m < 4; ++m)
#pragma unroll
        for (int n = 0; n < 4; ++n)
            acc[m][n] = (f32x4){0.f, 0.f, 0.f, 0.f};

    for (int k0 = 0; k0 < K; k0 += 64) {
#pragma unroll
        for (int c = 0; c < 4; ++c) {
            int chunk = tid + 256 * c;            // 0..1023
            int row = chunk >> 3;                 // 0..127
            int kc = (chunk & 7) * 8;             // bf16 col 0,8,..,56
            uint4 av = *reinterpret_cast<const uint4*>(A + (size_t)(m0 + row) * lda + k0 + kc);
            int byte = (row * 128 + kc * 2) ^ ((row & 7) << 4);
            *reinterpret_cast<uint4*>(reinterpret_cast<char*>(Asm) + byte) = av;
            int nrow = n0 + row;
            uint4 bv = make_uint4(0u, 0u, 0u, 0u);
            if (nrow < N) bv = *reinterpret_cast<const uint4*>(Bw + (size_t)nrow * ldb + k0 + kc);
            *reinterpret_cast<uint4*>(reinterpret_cast<char*>(Bsm) + byte) = bv;
        }
        __syncthreads();
#pragma unroll
        for (int kk = 0; kk < 2; ++kk) {
            short8v af[4], bf[4];
#pragma unroll
            for (int m = 0; m < 4; ++m) {
                int row = wr * 64 + m * 16 + (lane & 15);
                int byte = (row * 128 + kk * 64 + (lane >> 4) * 16) ^ ((row & 7) << 4);
                af[m] = *reinterpret_cast<const short8v*>(reinterpret_cast<char*>(Asm) + byte);
            }
#pragma unroll
            for (int n = 0; n < 4; ++n) {
                int row = wc * 64 + n * 16 + (lane & 15);
                int byte = (row * 128 + kk * 64 + (lane >> 4) * 16) ^ ((row & 7) << 4);
                bf[n] = *reinterpret_cast<const short8v*>(reinterpret_cast<char*>(Bsm) + byte);
            }
#pragma unroll
            for (int m = 0; m < 4; ++m)
#pragma unroll
                for (int n = 0; n < 4; ++n)
                    acc[m][n] = __builtin_amdgcn_mfma_f32_16x16x32_bf16(af[m], bf[n], acc[m][n], 0, 0, 0);
        }
        __syncthreads();
    }

#pragma unroll
    for (int m = 0; m < 4; ++m) {
        int row0 = m0 + wr * 64 + m * 16 + (lane >> 4) * 4;
#pragma unroll
        for (int n = 0; n < 4; ++n) {
            int col = n0 + wc * 64 + n * 16 + (lane & 15);
            if (col < N) {
                if (STORE_MODE == 0) {
                    float* C = (float*)Cout;
#pragma unroll
                    for (int r = 0; r < 4; ++r)
                        C[(size_t)(row0 + r) * ldc + col] = acc[m][n][r];
                } else if (STORE_MODE == 1) {
                    float* C = (float*)Cout;
                    int b = row0 / LDIM, l = row0 % LDIM;
                    float4 v = make_float4(acc[m][n][0], acc[m][n][1], acc[m][n][2], acc[m][n][3]);
                    *reinterpret_cast<float4*>(C + ((size_t)(b * CDIM + col)) * LDIM + l) = v;
                } else {
                    unsigned short* C = (unsigned short*)Cout;
#pragma unroll
                    for (int r = 0; r < 4; ++r)
                        C[(size_t)(row0 + r) * ldc + col] = f2bf(acc[m][n][r]);
                }
            }
        }
    }
}

// ---------------- double LayerNorm [P,256] fp32 -> bf16 ---------------------
__device__ __forceinline__ float block_sum256(float v, float* sm) {
#pragma unroll
    for (int m = 32; m; m >>= 1) v += __shfl_xor(v, m);
    __syncthreads();
    if ((threadIdx.x & 63) == 0) sm[threadIdx.x >> 6] = v;
    __syncthreads();
    return sm[0] + sm[1] + sm[2] + sm[3];
}

__global__ __launch_bounds__(256)
void k_ln2(const float* __restrict__ xs,
           const float* __restrict__ g1, const float* __restrict__ b1,
           const float* __restrict__ g2, const float* __restrict__ b2,
           unsigned short* __restrict__ xsb)
{
    __shared__ float sm[4];
    int p = blockIdx.x;
    int c = threadIdx.x;
    float v = xs[(size_t)p * CDIM + c];
    float mu = block_sum256(v, sm) * (1.f / CDIM);
    float dv = v - mu;
    float var = block_sum256(dv * dv, sm) * (1.f / CDIM);
    float y = dv * rsqrtf(var + 1e-5f) * g1[c] + b1[c];
    float mu2 = block_sum256(y, sm) * (1.f / CDIM);
    float dy = y - mu2;
    float var2 = block_sum256(dy * dy, sm) * (1.f / CDIM);
    float y2 = dy * rsqrtf(var2 + 1e-5f) * g2[c] + b2[c];
    xsb[(size_t)p * CDIM + c] = f2bf(y2);
}

// ---------------- causal depthwise conv1d + SiLU (bf16 in, f32+bf16 out) ----
__global__ void k_conv1d(const unsigned short* __restrict__ xz, const float* __restrict__ wc,
                         const float* __restrict__ bc,
                         float* __restrict__ xcf, unsigned short* __restrict__ xcb)
{
    int idx = blockIdx.x * 256 + threadIdx.x;       // over P*512
    int d = idx & 511;
    int p = idx >> 9;
    int b = p / LDIM, l = p % LDIM;
    float4 w = *reinterpret_cast<const float4*>(wc + d * 4);
    const unsigned short* base = xz + (size_t)(b * LDIM) * 1024 + d;
    float acc = bc[d];
    if (l >= 3) acc = fmaf(b2f(base[(size_t)(l - 3) * 1024]), w.x, acc);
    if (l >= 2) acc = fmaf(b2f(base[(size_t)(l - 2) * 1024]), w.y, acc);
    if (l >= 1) acc = fmaf(b2f(base[(size_t)(l - 1) * 1024]), w.z, acc);
    acc = fmaf(b2f(base[(size_t)l * 1024]), w.w, acc);
    float sig = 1.f / (1.f + __expf(-acc));
    float v = acc * sig;
    xcf[(size_t)p * DI + d] = v;
    xcb[(size_t)p * DI + d] = f2bf(v);
}

// ---------------- dt = softplus(dbc[:, :16] @ w_dt^T + b_dt) -> bf16 --------
__global__ void k_dt(const float* __restrict__ dbc, const float* __restrict__ wdt,
                     const float* __restrict__ bdt, unsigned short* __restrict__ dtout)
{
    int idx = blockIdx.x * 256 + threadIdx.x;       // over P*512
    int d = idx & 511;
    int p = idx >> 9;
    const float* r = dbc + (size_t)p * HH;
    const float* w = wdt + d * 16;
    float acc = bdt[d];
#pragma unroll
    for (int k = 0; k < 16; ++k) acc = fmaf(r[k], w[k], acc);
    float sp = fmaxf(acc, 0.f) + log1pf(__expf(-fabsf(acc)));
    dtout[(size_t)p * 1024 + d] = f2bf(sp);
}

// ---------------- segmented selective scan ----------------------------------
__global__ __launch_bounds__(256)
void k_scan_p1(const unsigned short* __restrict__ xz,   // dt bf16 at [p*1024+d]
               const float* __restrict__ dbc,           // B at [p*48+16+s]
               const float* __restrict__ Alog,
               const float* __restrict__ xc,
               float* __restrict__ aprod, float* __restrict__ hout)
{
    int t = blockIdx.x * 256 + threadIdx.x;        // 98304
    int d = t & 511;
    int rest = t >> 9;
    int b = rest / NSEG, seg = rest % NSEG;
    int l0 = seg * SEGLEN;
    float A[16], h[16], ap[16];
#pragma unroll
    for (int i = 0; i < 4; ++i) {
        float4 v = *reinterpret_cast<const float4*>(Alog + d * 16 + i * 4);
        A[4*i+0] = -__expf(v.x); A[4*i+1] = -__expf(v.y);
        A[4*i+2] = -__expf(v.z); A[4*i+3] = -__expf(v.w);
    }
#pragma unroll
    for (int s = 0; s < 16; ++s) { h[s] = 0.f; ap[s] = 1.f; }
    const unsigned short* dtp = xz + (size_t)(b * LDIM) * 1024;
    const float* xcp  = xc  + (size_t)(b * LDIM) * DI;
    const float* dbcb = dbc + (size_t)(b * LDIM) * HH;
    for (int i = 0; i < SEGLEN; ++i) {
        int l = l0 + i;
        float dt = b2f(dtp[(size_t)l * 1024 + d]);
        float xv = xcp[(size_t)l * DI + d];
        float4 B0 = *reinterpret_cast<const float4*>(dbcb + l * HH + 16);
        float4 B1 = *reinterpret_cast<const float4*>(dbcb + l * HH + 20);
        float4 B2 = *reinterpret_cast<const float4*>(dbcb + l * HH + 24);
        float4 B3 = *reinterpret_cast<const float4*>(dbcb + l * HH + 28);
        float Bv[16] = {B0.x,B0.y,B0.z,B0.w, B1.x,B1.y,B1.z,B1.w,
                        B2.x,B2.y,B2.z,B2.w, B3.x,B3.y,B3.z,B3.w};
        float dtx = dt * xv;
#pragma unroll
        for (int s = 0; s < 16; ++s) {
            float dA = __expf(dt * A[s]);
            h[s] = fmaf(dA, h[s], dtx * Bv[s]);
            ap[s] *= dA;
        }
    }
    size_t base = ((size_t)((b * DI + d) * NSEG) + seg) * 16;
    float4* apo = reinterpret_cast<float4*>(aprod + base);
    float4* hoo = reinterpret_cast<float4*>(hout + base);
#pragma unroll
    for (int i = 0; i < 4; ++i) {
        apo[i] = make_float4(ap[4*i], ap[4*i+1], ap[4*i+2], ap[4*i+3]);
        hoo[i] = make_float4(h[4*i],  h[4*i+1],  h[4*i+2],  h[4*i+3]);
    }
}

__global__ __launch_bounds__(256)
void k_scan_p2(float* __restrict__ aprod, const float* __restrict__ hout)
{
    int t = blockIdx.x * 256 + threadIdx.x;        // 65536
    int s = t & 15;
    int g = t >> 4;
    float h = 0.f;
    for (int seg = 0; seg < NSEG; ++seg) {
        size_t idx = ((size_t)g * NSEG + seg) * 16 + s;
        float a  = aprod[idx];
        float ho = hout[idx];
        aprod[idx] = h;
        h = fmaf(a, h, ho);
    }
}

__global__ __launch_bounds__(256)
void k_scan_p3(const unsigned short* __restrict__ xz,   // dt bf16, z bf16 at +512
               const float* __restrict__ dbc,
               const float* __restrict__ Alog,
               const float* __restrict__ Dp,
               const float* __restrict__ hinit,
               const float* __restrict__ xc,
               unsigned short* __restrict__ yb)
{
    int t = blockIdx.x * 256 + threadIdx.x;
    int d = t & 511;
    int rest = t >> 9;
    int b = rest / NSEG, seg = rest % NSEG;
    int l0 = seg * SEGLEN;
    float A[16], h[16];
#pragma unroll
    for (int i = 0; i < 4; ++i) {
        float4 v = *reinterpret_cast<const float4*>(Alog + d * 16 + i * 4);
        A[4*i+0] = -__expf(v.x); A[4*i+1] = -__expf(v.y);
        A[4*i+2] = -__expf(v.z); A[4*i+3] = -__expf(v.w);
    }
    size_t base = ((size_t)((b * DI + d) * NSEG) + seg) * 16;
#pragma unroll
    for (int i = 0; i < 4; ++i) {
        float4 v = *reinterpret_cast<const float4*>(hinit + base + 4 * i);
        h[4*i+0] = v.x; h[4*i+1] = v.y; h[4*i+2] = v.z; h[4*i+3] = v.w;
    }
    float Dv = Dp[d];
    const unsigned short* dtp = xz + (size_t)(b * LDIM) * 1024;
    const float* dbcb = dbc + (size_t)(b * LDIM) * HH;
    const float* xcb = xc + (size_t)(b * LDIM) * DI;
    unsigned short* yo = yb + (size_t)(b * LDIM) * DI;
    for (int i = 0; i < SEGLEN; ++i) {
        int l = l0 + i;
        float dt = b2f(dtp[(size_t)l * 1024 + d]);
        float zv = b2f(dtp[(size_t)l * 1024 + 512 + d]);
        float xv = xcb[(size_t)l * DI + d];
        float4 B0 = *reinterpret_cast<const float4*>(dbcb + l * HH + 16);
        float4 B1 = *reinterpret_cast<const float4*>(dbcb + l * HH + 20);
        float4 B2 = *reinterpret_cast<const float4*>(dbcb + l * HH + 24);
        float4 B3 = *reinterpret_cast<const float4*>(dbcb + l * HH + 28);
        float4 C0 = *reinterpret_cast<const float4*>(dbcb + l * HH + 32);
        float4 C1 = *reinterpret_cast<const float4*>(dbcb + l * HH + 36);
        float4 C2 = *reinterpret_cast<const float4*>(dbcb + l * HH + 40);
        float4 C3 = *reinterpret_cast<const float4*>(dbcb + l * HH + 44);
        float Bv[16] = {B0.x,B0.y,B0.z,B0.w, B1.x,B1.y,B1.z,B1.w,
                        B2.x,B2.y,B2.z,B2.w, B3.x,B3.y,B3.z,B3.w};
        float Cv[16] = {C0.x,C0.y,C0.z,C0.w, C1.x,C1.y,C1.z,C1.w,
                        C2.x,C2.y,C2.z,C2.w, C3.x,C3.y,C3.z,C3.w};
        float dtx = dt * xv;
        float y = 0.f;
#pragma unroll
        for (int s = 0; s < 16; ++s) {
            float dA = __expf(dt * A[s]);
            h[s] = fmaf(dA, h[s], dtx * Bv[s]);
            y = fmaf(h[s], Cv[s], y);
        }
        y = fmaf(xv, Dv, y);
        float sig = 1.f / (1.f + __expf(-zv));
        yo[(size_t)l * DI + d] = f2bf(y * (zv * sig));
    }
}

extern "C" void kernel_launch(void* const* d_in, const int* in_sizes, int n_in,
                              void* d_out, int out_size, void* d_ws, size_t ws_size,
                              hipStream_t stream) {
    const float* x      = (const float*)d_in[0];
    const float* w_down = (const float*)d_in[1];
    const float* g1     = (const float*)d_in[2];
    const float* b1     = (const float*)d_in[3];
    const float* g2     = (const float*)d_in[4];
    const float* b2     = (const float*)d_in[5];
    const float* w_in   = (const float*)d_in[6];
    const float* w_conv = (const float*)d_in[7];
    const float* b_conv = (const float*)d_in[8];
    const float* w_xprj = (const float*)d_in[9];
    const float* w_dt   = (const float*)d_in[10];
    const float* b_dt   = (const float*)d_in[11];
    const float* A_log  = (const float*)d_in[12];
    const float* Dp     = (const float*)d_in[13];
    const float* w_out  = (const float*)d_in[14];
    float* out = (float*)d_out;

    // ws layout (bytes from base), total 105.2 MB < 113.25 MB proven budget:
    char* wsb = (char*)d_ws;
    unsigned short* R0  = (unsigned short*)wsb;                      // [P,1024] bf16: im2col A1, then xz (dt in xm half)
    unsigned short* R1  = (unsigned short*)(wsb + 37748736);         // [P,256]  bf16: xs
    float*          R2  = (float*)(wsb + 47185920);                  // [P,512]  fp32: xc
    unsigned short* R3  = (unsigned short*)(wsb + 84934656);         // [P,512]  bf16: xc_bf16, then y_bf16
    unsigned short* Wb  = (unsigned short*)(wsb + 103809024);        // weights bf16
    unsigned short* wdownb = Wb;                                     // 262144
    unsigned short* winb   = Wb + 262144;                            // 262144
    unsigned short* wxb    = Wb + 524288;                            // 24576
    unsigned short* woutb  = Wb + 548864;                            // 131072

    // segment scratch in dead region of d_out (dbc uses [0, P*48) floats)
    float* aprod = out + (size_t)PDIM * HH;                          // 1572864 floats
    float* hout  = aprod + (size_t)BDIM * DI * NSEG * 16;            // 1572864 floats

    // 0. weight casts
    k_cast<<<1024, 256, 0, stream>>>(w_down, wdownb, 262144);
    k_cast<<<1024, 256, 0, stream>>>(w_in,   winb,   262144);
    k_cast<<<96,   256, 0, stream>>>(w_xprj, wxb,    24576);
    k_cast<<<512,  256, 0, stream>>>(w_out,  woutb,  131072);
    // 1. im2col -> bf16 A1 (R0)
    k_im2col<<<PDIM * CDIM / 256, 256, 0, stream>>>(x, R0);
    // 2. xd = A1 @ w_down^T -> d_out fp32 [P,256]
    k_gemm_mfma<0><<<dim3(144, 2), 256, 0, stream>>>(R0, 1024, wdownb, 1024, out, 256, 256, 1024);
    // 3. double LayerNorm -> xs bf16 (R1)
    k_ln2<<<PDIM, 256, 0, stream>>>(out, g1, b1, g2, b2, R1);
    // 4. xz = xs @ w_in^T -> R0 bf16 [P,1024]
    k_gemm_mfma<2><<<dim3(144, 8), 256, 0, stream>>>(R1, 256, winb, 256, R0, 1024, 1024, 256);
    // 5. conv1d + SiLU -> xc fp32 (R2) + bf16 (R3)
    k_conv1d<<<PDIM * DI / 256, 256, 0, stream>>>(R0, w_conv, b_conv, R2, R3);
    // 6. dbc = xc @ w_xproj^T -> d_out fp32 [P,48]
    k_gemm_mfma<0><<<dim3(144, 1), 256, 0, stream>>>(R3, 512, wxb, 512, out, HH, HH, 512);
    // 7. dt = softplus(...) -> bf16 into xm half of R0
    k_dt<<<PDIM * DI / 256, 256, 0, stream>>>(out, w_dt, b_dt, R0);
    // 8. segmented scan + gating -> y bf16 (R3, overwrites dead xc_bf16)
    k_scan_p1<<<BDIM * NSEG * DI / 256, 256, 0, stream>>>(R0, out, A_log, R2, aprod, hout);
    k_scan_p2<<<BDIM * DI * 16 / 256, 256, 0, stream>>>(aprod, hout);
    k_scan_p3<<<BDIM * NSEG * DI / 256, 256, 0, stream>>>(R0, out, A_log, Dp, aprod, R2, R3);
    // 9. out = y @ w_out^T, transposed store to [B,C,48,48]
    k_gemm_mfma<1><<<dim3(144, 2), 256, 0, stream>>>(R3, 512, woutb, 512, out, 0, 256, 512);
}

// Round 4
// 428.742 us; speedup vs baseline: 5.6261x; 1.1410x over previous
//
#include <hip/hip_runtime.h>
#include <math.h>

#define PDIM 18432      // B*L
#define LDIM 2304
#define BDIM 8
#define CDIM 256
#define DI   512
#define DS   16
#define HH   48         // dt_rank + 2*d_state

#define NSEG 64
#define SEGLEN 36       // LDIM / NSEG

typedef short short8v __attribute__((ext_vector_type(8)));
typedef float f32x4 __attribute__((ext_vector_type(4)));

__device__ __forceinline__ unsigned short f2bf(float f) {
    unsigned u = __float_as_uint(f);
    unsigned r = (u + 0x7fff + ((u >> 16) & 1)) >> 16;
    return (unsigned short)r;
}
__device__ __forceinline__ float b2f(unsigned short u) {
    return __uint_as_float(((unsigned)u) << 16);
}

// ---------------- fp32 -> bf16 cast (weights) -------------------------------
__global__ void k_cast(const float* __restrict__ src, unsigned short* __restrict__ dst, int n) {
    int i = blockIdx.x * 256 + threadIdx.x;
    if (i < n) dst[i] = f2bf(src[i]);
}

// ---------------- im2col -> bf16 [P,1024], k=(c,kh,kw) ----------------------
__global__ void k_im2col(const float* __restrict__ x, unsigned short* __restrict__ out) {
    int idx = blockIdx.x * 256 + threadIdx.x;       // over P*256
    int c = idx & 255;
    int p = idx >> 8;
    int b = p / LDIM;
    int l = p % LDIM;
    int i2 = l / 48, j2 = l % 48;
    const float* src = x + ((size_t)(b * CDIM + c) * 96 + 2 * i2) * 96 + 2 * j2;
    ushort4 v;
    v.x = f2bf(src[0]); v.y = f2bf(src[1]); v.z = f2bf(src[96]); v.w = f2bf(src[97]);
    *reinterpret_cast<ushort4*>(out + (size_t)p * 1024 + c * 4) = v;
}

// ---------------- bf16 MFMA GEMM: C[M,N] = A[M,K] * B[N,K]^T ----------------
// 128x128 tile, BK=64, 4 waves each owning 64x64 (4x4 frags of 16x16x32).
// STORE_MODE 0: fp32 row-major; 1: fp32 transposed [(b*256+n)*2304+l]; 2: bf16 row-major
template<int STORE_MODE>
__global__ __launch_bounds__(256)
void k_gemm_mfma(const unsigned short* __restrict__ A, int lda,
                 const unsigned short* __restrict__ Bw, int ldb,
                 void* __restrict__ Cout, int ldc,
                 int N, int K)
{
    __shared__ __align__(16) unsigned short Asm[128 * 64];
    __shared__ __align__(16) unsigned short Bsm[128 * 64];
    int m0 = blockIdx.x * 128;
    int n0 = blockIdx.y * 128;
    int tid = threadIdx.x;
    int lane = tid & 63;
    int wid = tid >> 6;
    int wr = wid >> 1, wc = wid & 1;

    f32x4 acc[4][4];
#pragma unroll
    for (int m = 0; m < 4; ++m)
#pragma unroll
        for (int n = 0; n < 4; ++n)
            acc[m][n] = (f32x4){0.f, 0.f, 0.f, 0.f};

    for (int k0 = 0; k0 < K; k0 += 64) {
#pragma unroll
        for (int c = 0; c < 4; ++c) {
            int chunk = tid + 256 * c;            // 0..1023
            int row = chunk >> 3;                 // 0..127
            int kc = (chunk & 7) * 8;             // bf16 col 0,8,..,56
            uint4 av = *reinterpret_cast<const uint4*>(A + (size_t)(m0 + row) * lda + k0 + kc);
            int byte = (row * 128 + kc * 2) ^ ((row & 7) << 4);
            *reinterpret_cast<uint4*>(reinterpret_cast<char*>(Asm) + byte) = av;
            int nrow = n0 + row;
            uint4 bv = make_uint4(0u, 0u, 0u, 0u);
            if (nrow < N) bv = *reinterpret_cast<const uint4*>(Bw + (size_t)nrow * ldb + k0 + kc);
            *reinterpret_cast<uint4*>(reinterpret_cast<char*>(Bsm) + byte) = bv;
        }
        __syncthreads();
#pragma unroll
        for (int kk = 0; kk < 2; ++kk) {
            short8v af[4], bf[4];
#pragma unroll
            for (int m = 0; m < 4; ++m) {
                int row = wr * 64 + m * 16 + (lane & 15);
                int byte = (row * 128 + kk * 64 + (lane >> 4) * 16) ^ ((row & 7) << 4);
                af[m] = *reinterpret_cast<const short8v*>(reinterpret_cast<char*>(Asm) + byte);
            }
#pragma unroll
            for (int n = 0; n < 4; ++n) {
                int row = wc * 64 + n * 16 + (lane & 15);
                int byte = (row * 128 + kk * 64 + (lane >> 4) * 16) ^ ((row & 7) << 4);
                bf[n] = *reinterpret_cast<const short8v*>(reinterpret_cast<char*>(Bsm) + byte);
            }
#pragma unroll
            for (int m = 0; m < 4; ++m)
#pragma unroll
                for (int n = 0; n < 4; ++n)
                    acc[m][n] = __builtin_amdgcn_mfma_f32_16x16x32_bf16(af[m], bf[n], acc[m][n], 0, 0, 0);
        }
        __syncthreads();
    }

#pragma unroll
    for (int m = 0; m < 4; ++m) {
        int row0 = m0 + wr * 64 + m * 16 + (lane >> 4) * 4;
#pragma unroll
        for (int n = 0; n < 4; ++n) {
            int col = n0 + wc * 64 + n * 16 + (lane & 15);
            if (col < N) {
                if (STORE_MODE == 0) {
                    float* C = (float*)Cout;
#pragma unroll
                    for (int r = 0; r < 4; ++r)
                        C[(size_t)(row0 + r) * ldc + col] = acc[m][n][r];
                } else if (STORE_MODE == 1) {
                    float* C = (float*)Cout;
                    int b = row0 / LDIM, l = row0 % LDIM;
                    float4 v = make_float4(acc[m][n][0], acc[m][n][1], acc[m][n][2], acc[m][n][3]);
                    *reinterpret_cast<float4*>(C + ((size_t)(b * CDIM + col)) * LDIM + l) = v;
                } else {
                    unsigned short* C = (unsigned short*)Cout;
#pragma unroll
                    for (int r = 0; r < 4; ++r)
                        C[(size_t)(row0 + r) * ldc + col] = f2bf(acc[m][n][r]);
                }
            }
        }
    }
}

// ---------------- double LayerNorm [P,256] fp32 -> bf16 ---------------------
__device__ __forceinline__ float block_sum256(float v, float* sm) {
#pragma unroll
    for (int m = 32; m; m >>= 1) v += __shfl_xor(v, m);
    __syncthreads();
    if ((threadIdx.x & 63) == 0) sm[threadIdx.x >> 6] = v;
    __syncthreads();
    return sm[0] + sm[1] + sm[2] + sm[3];
}

__global__ __launch_bounds__(256)
void k_ln2(const float* __restrict__ xs,
           const float* __restrict__ g1, const float* __restrict__ b1,
           const float* __restrict__ g2, const float* __restrict__ b2,
           unsigned short* __restrict__ xsb)
{
    __shared__ float sm[4];
    int p = blockIdx.x;
    int c = threadIdx.x;
    float v = xs[(size_t)p * CDIM + c];
    float mu = block_sum256(v, sm) * (1.f / CDIM);
    float dv = v - mu;
    float var = block_sum256(dv * dv, sm) * (1.f / CDIM);
    float y = dv * rsqrtf(var + 1e-5f) * g1[c] + b1[c];
    float mu2 = block_sum256(y, sm) * (1.f / CDIM);
    float dy = y - mu2;
    float var2 = block_sum256(dy * dy, sm) * (1.f / CDIM);
    float y2 = dy * rsqrtf(var2 + 1e-5f) * g2[c] + b2[c];
    xsb[(size_t)p * CDIM + c] = f2bf(y2);
}

// ---------------- causal depthwise conv1d + SiLU (bf16 in, bf16 out) --------
__global__ void k_conv1d(const unsigned short* __restrict__ xz, const float* __restrict__ wc,
                         const float* __restrict__ bc, unsigned short* __restrict__ xcb)
{
    int idx = blockIdx.x * 256 + threadIdx.x;       // over P*512
    int d = idx & 511;
    int p = idx >> 9;
    int b = p / LDIM, l = p % LDIM;
    float4 w = *reinterpret_cast<const float4*>(wc + d * 4);
    const unsigned short* base = xz + (size_t)(b * LDIM) * 1024 + d;
    float acc = bc[d];
    if (l >= 3) acc = fmaf(b2f(base[(size_t)(l - 3) * 1024]), w.x, acc);
    if (l >= 2) acc = fmaf(b2f(base[(size_t)(l - 2) * 1024]), w.y, acc);
    if (l >= 1) acc = fmaf(b2f(base[(size_t)(l - 1) * 1024]), w.z, acc);
    acc = fmaf(b2f(base[(size_t)l * 1024]), w.w, acc);
    float sig = 1.f / (1.f + __expf(-acc));
    xcb[(size_t)p * DI + d] = f2bf(acc * sig);
}

// ---------------- dt = softplus(dbc[:, :16] @ w_dt^T + b_dt) -> bf16 --------
__global__ void k_dt(const float* __restrict__ dbc, const float* __restrict__ wdt,
                     const float* __restrict__ bdt, unsigned short* __restrict__ dtout)
{
    int idx = blockIdx.x * 256 + threadIdx.x;       // over P*512
    int d = idx & 511;
    int p = idx >> 9;
    const float* r = dbc + (size_t)p * HH;
    const float* w = wdt + d * 16;
    float acc = bdt[d];
#pragma unroll
    for (int k = 0; k < 16; ++k) acc = fmaf(r[k], w[k], acc);
    float sp = fmaxf(acc, 0.f) + log1pf(__expf(-fabsf(acc)));
    dtout[(size_t)p * 1024 + d] = f2bf(sp);
}

// ---------------- segmented selective scan ----------------------------------
__global__ __launch_bounds__(256)
void k_scan_p1(const unsigned short* __restrict__ xz,   // dt bf16 at [p*1024+d]
               const float* __restrict__ dbc,           // B at [p*48+16+s]
               const float* __restrict__ Alog,
               const unsigned short* __restrict__ xc,   // bf16
               float* __restrict__ aprod, float* __restrict__ hout)
{
    int t = blockIdx.x * 256 + threadIdx.x;        // 262144
    int d = t & 511;
    int rest = t >> 9;
    int b = rest / NSEG, seg = rest % NSEG;
    int l0 = seg * SEGLEN;
    float A[16], h[16], ap[16];
#pragma unroll
    for (int i = 0; i < 4; ++i) {
        float4 v = *reinterpret_cast<const float4*>(Alog + d * 16 + i * 4);
        A[4*i+0] = -__expf(v.x); A[4*i+1] = -__expf(v.y);
        A[4*i+2] = -__expf(v.z); A[4*i+3] = -__expf(v.w);
    }
#pragma unroll
    for (int s = 0; s < 16; ++s) { h[s] = 0.f; ap[s] = 1.f; }
    const unsigned short* dtp = xz + (size_t)(b * LDIM) * 1024;
    const unsigned short* xcp = xc + (size_t)(b * LDIM) * DI;
    const float* dbcb = dbc + (size_t)(b * LDIM) * HH;
    for (int i = 0; i < SEGLEN; ++i) {
        int l = l0 + i;
        float dt = b2f(dtp[(size_t)l * 1024 + d]);
        float xv = b2f(xcp[(size_t)l * DI + d]);
        float4 B0 = *reinterpret_cast<const float4*>(dbcb + l * HH + 16);
        float4 B1 = *reinterpret_cast<const float4*>(dbcb + l * HH + 20);
        float4 B2 = *reinterpret_cast<const float4*>(dbcb + l * HH + 24);
        float4 B3 = *reinterpret_cast<const float4*>(dbcb + l * HH + 28);
        float Bv[16] = {B0.x,B0.y,B0.z,B0.w, B1.x,B1.y,B1.z,B1.w,
                        B2.x,B2.y,B2.z,B2.w, B3.x,B3.y,B3.z,B3.w};
        float dtx = dt * xv;
#pragma unroll
        for (int s = 0; s < 16; ++s) {
            float dA = __expf(dt * A[s]);
            h[s] = fmaf(dA, h[s], dtx * Bv[s]);
            ap[s] *= dA;
        }
    }
    size_t base = ((size_t)((b * DI + d) * NSEG) + seg) * 16;
    float4* apo = reinterpret_cast<float4*>(aprod + base);
    float4* hoo = reinterpret_cast<float4*>(hout + base);
#pragma unroll
    for (int i = 0; i < 4; ++i) {
        apo[i] = make_float4(ap[4*i], ap[4*i+1], ap[4*i+2], ap[4*i+3]);
        hoo[i] = make_float4(h[4*i],  h[4*i+1],  h[4*i+2],  h[4*i+3]);
    }
}

__global__ __launch_bounds__(256)
void k_scan_p2(float* __restrict__ aprod, const float* __restrict__ hout)
{
    int t = blockIdx.x * 256 + threadIdx.x;        // 65536
    int s = t & 15;
    int g = t >> 4;
    float h = 0.f;
    for (int seg = 0; seg < NSEG; ++seg) {
        size_t idx = ((size_t)g * NSEG + seg) * 16 + s;
        float a  = aprod[idx];
        float ho = hout[idx];
        aprod[idx] = h;
        h = fmaf(a, h, ho);
    }
}

__global__ __launch_bounds__(256)
void k_scan_p3(const unsigned short* __restrict__ xz,   // dt bf16, z bf16 at +512
               const float* __restrict__ dbc,
               const float* __restrict__ Alog,
               const float* __restrict__ Dp,
               const float* __restrict__ hinit,
               unsigned short* __restrict__ xc_y)       // in: xc bf16; out: y bf16 in place
{
    int t = blockIdx.x * 256 + threadIdx.x;
    int d = t & 511;
    int rest = t >> 9;
    int b = rest / NSEG, seg = rest % NSEG;
    int l0 = seg * SEGLEN;
    float A[16], h[16];
#pragma unroll
    for (int i = 0; i < 4; ++i) {
        float4 v = *reinterpret_cast<const float4*>(Alog + d * 16 + i * 4);
        A[4*i+0] = -__expf(v.x); A[4*i+1] = -__expf(v.y);
        A[4*i+2] = -__expf(v.z); A[4*i+3] = -__expf(v.w);
    }
    size_t base = ((size_t)((b * DI + d) * NSEG) + seg) * 16;
#pragma unroll
    for (int i = 0; i < 4; ++i) {
        float4 v = *reinterpret_cast<const float4*>(hinit + base + 4 * i);
        h[4*i+0] = v.x; h[4*i+1] = v.y; h[4*i+2] = v.z; h[4*i+3] = v.w;
    }
    float Dv = Dp[d];
    const unsigned short* dtp = xz + (size_t)(b * LDIM) * 1024;
    const float* dbcb = dbc + (size_t)(b * LDIM) * HH;
    unsigned short* xcb = xc_y + (size_t)(b * LDIM) * DI;
    for (int i = 0; i < SEGLEN; ++i) {
        int l = l0 + i;
        float dt = b2f(dtp[(size_t)l * 1024 + d]);
        float zv = b2f(dtp[(size_t)l * 1024 + 512 + d]);
        float xv = b2f(xcb[(size_t)l * DI + d]);
        float4 B0 = *reinterpret_cast<const float4*>(dbcb + l * HH + 16);
        float4 B1 = *reinterpret_cast<const float4*>(dbcb + l * HH + 20);
        float4 B2 = *reinterpret_cast<const float4*>(dbcb + l * HH + 24);
        float4 B3 = *reinterpret_cast<const float4*>(dbcb + l * HH + 28);
        float4 C0 = *reinterpret_cast<const float4*>(dbcb + l * HH + 32);
        float4 C1 = *reinterpret_cast<const float4*>(dbcb + l * HH + 36);
        float4 C2 = *reinterpret_cast<const float4*>(dbcb + l * HH + 40);
        float4 C3 = *reinterpret_cast<const float4*>(dbcb + l * HH + 44);
        float Bv[16] = {B0.x,B0.y,B0.z,B0.w, B1.x,B1.y,B1.z,B1.w,
                        B2.x,B2.y,B2.z,B2.w, B3.x,B3.y,B3.z,B3.w};
        float Cv[16] = {C0.x,C0.y,C0.z,C0.w, C1.x,C1.y,C1.z,C1.w,
                        C2.x,C2.y,C2.z,C2.w, C3.x,C3.y,C3.z,C3.w};
        float dtx = dt * xv;
        float y = 0.f;
#pragma unroll
        for (int s = 0; s < 16; ++s) {
            float dA = __expf(dt * A[s]);
            h[s] = fmaf(dA, h[s], dtx * Bv[s]);
            y = fmaf(h[s], Cv[s], y);
        }
        y = fmaf(xv, Dv, y);
        float sig = 1.f / (1.f + __expf(-zv));
        xcb[(size_t)l * DI + d] = f2bf(y * (zv * sig));
    }
}

extern "C" void kernel_launch(void* const* d_in, const int* in_sizes, int n_in,
                              void* d_out, int out_size, void* d_ws, size_t ws_size,
                              hipStream_t stream) {
    const float* x      = (const float*)d_in[0];
    const float* w_down = (const float*)d_in[1];
    const float* g1     = (const float*)d_in[2];
    const float* b1     = (const float*)d_in[3];
    const float* g2     = (const float*)d_in[4];
    const float* b2     = (const float*)d_in[5];
    const float* w_in   = (const float*)d_in[6];
    const float* w_conv = (const float*)d_in[7];
    const float* b_conv = (const float*)d_in[8];
    const float* w_xprj = (const float*)d_in[9];
    const float* w_dt   = (const float*)d_in[10];
    const float* b_dt   = (const float*)d_in[11];
    const float* A_log  = (const float*)d_in[12];
    const float* Dp     = (const float*)d_in[13];
    const float* w_out  = (const float*)d_in[14];
    float* out = (float*)d_out;

    // ws layout (bytes from base), total ~101 MB < 113.25 MB proven budget:
    char* wsb = (char*)d_ws;
    unsigned short* R0  = (unsigned short*)wsb;                      // [P,1024] bf16: im2col A1 -> xz (dt in xm half)
    unsigned short* R1  = (unsigned short*)(wsb + 37748736);         // [P,256]  bf16: xs
    unsigned short* R3  = (unsigned short*)(wsb + 47185920);         // [P,512]  bf16: xc -> y (in place)
    float*          aprod = (float*)(wsb + 66060288);                // 4.19M floats (16.78 MB)
    float*          hout  = (float*)(wsb + 82837504);                // 4.19M floats (16.78 MB)
    unsigned short* Wb  = (unsigned short*)(wsb + 99614720);         // weights bf16 (1.36 MB)
    unsigned short* wdownb = Wb;                                     // 262144
    unsigned short* winb   = Wb + 262144;                            // 262144
    unsigned short* wxb    = Wb + 524288;                            // 24576
    unsigned short* woutb  = Wb + 548864;                            // 131072

    // 0. weight casts
    k_cast<<<1024, 256, 0, stream>>>(w_down, wdownb, 262144);
    k_cast<<<1024, 256, 0, stream>>>(w_in,   winb,   262144);
    k_cast<<<96,   256, 0, stream>>>(w_xprj, wxb,    24576);
    k_cast<<<512,  256, 0, stream>>>(w_out,  woutb,  131072);
    // 1. im2col -> bf16 A1 (R0)
    k_im2col<<<PDIM * CDIM / 256, 256, 0, stream>>>(x, R0);
    // 2. xd = A1 @ w_down^T -> d_out fp32 [P,256]
    k_gemm_mfma<0><<<dim3(144, 2), 256, 0, stream>>>(R0, 1024, wdownb, 1024, out, 256, 256, 1024);
    // 3. double LayerNorm -> xs bf16 (R1)
    k_ln2<<<PDIM, 256, 0, stream>>>(out, g1, b1, g2, b2, R1);
    // 4. xz = xs @ w_in^T -> R0 bf16 [P,1024]
    k_gemm_mfma<2><<<dim3(144, 8), 256, 0, stream>>>(R1, 256, winb, 256, R0, 1024, 1024, 256);
    // 5. conv1d + SiLU -> xc bf16 (R3)
    k_conv1d<<<PDIM * DI / 256, 256, 0, stream>>>(R0, w_conv, b_conv, R3);
    // 6. dbc = xc @ w_xproj^T -> d_out fp32 [P,48]
    k_gemm_mfma<0><<<dim3(144, 1), 256, 0, stream>>>(R3, 512, wxb, 512, out, HH, HH, 512);
    // 7. dt = softplus(...) -> bf16 into xm half of R0
    k_dt<<<PDIM * DI / 256, 256, 0, stream>>>(out, w_dt, b_dt, R0);
    // 8. segmented scan + gating -> y bf16 in place over R3
    k_scan_p1<<<BDIM * NSEG * DI / 256, 256, 0, stream>>>(R0, out, A_log, R3, aprod, hout);
    k_scan_p2<<<BDIM * DI * 16 / 256, 256, 0, stream>>>(aprod, hout);
    k_scan_p3<<<BDIM * NSEG * DI / 256, 256, 0, stream>>>(R0, out, A_log, Dp, aprod, R3);
    // 9. out = y @ w_out^T, transposed store to [B,C,48,48]
    k_gemm_mfma<1><<<dim3(144, 2), 256, 0, stream>>>(R3, 512, woutb, 512, out, 0, 256, 512);
}

// Round 5
// 336.284 us; speedup vs baseline: 7.1729x; 1.2749x over previous
//
#include <hip/hip_runtime.h>
#include <math.h>

#define PDIM 18432      // B*L
#define LDIM 2304
#define BDIM 8
#define CDIM 256
#define DI   512
#define DS   16
#define HH   48         // dt_rank + 2*d_state

#define NSEG 64
#define SEGLEN 36       // LDIM / NSEG

typedef short short8v __attribute__((ext_vector_type(8)));
typedef float f32x4 __attribute__((ext_vector_type(4)));

__device__ __forceinline__ unsigned short f2bf(float f) {
    unsigned u = __float_as_uint(f);
    unsigned r = (u + 0x7fff + ((u >> 16) & 1)) >> 16;
    return (unsigned short)r;
}
__device__ __forceinline__ float b2f(unsigned short u) {
    return __uint_as_float(((unsigned)u) << 16);
}

// ---------------- fp32 -> bf16 cast (weights) -------------------------------
__global__ void k_cast(const float* __restrict__ src, unsigned short* __restrict__ dst, int n) {
    int i = blockIdx.x * 256 + threadIdx.x;
    if (i < n) dst[i] = f2bf(src[i]);
}

// ---------------- fused im2col + down-proj GEMM -----------------------------
// C[P,256] = im2col(x)[P,1024] @ w_down^T, A staged directly from x.
// x: [8,256,96,96] fp32; k = c*4 + kh*2 + kw matches w_down [O][I][2][2] flat.
__global__ __launch_bounds__(256)
void k_gemm_down(const float* __restrict__ X,
                 const unsigned short* __restrict__ Bw,
                 float* __restrict__ Cout)
{
    __shared__ __align__(16) unsigned short Asm[128 * 64];
    __shared__ __align__(16) unsigned short Bsm[128 * 64];
    int m0 = blockIdx.x * 128;
    int n0 = blockIdx.y * 128;
    int tid = threadIdx.x;
    int lane = tid & 63;
    int wid = tid >> 6;
    int wr = wid >> 1, wc = wid & 1;
    int bb = m0 / LDIM;                 // tile fully inside one b (2304 = 18*128)
    int rem0 = m0 % LDIM;
    const float* xb = X + (size_t)bb * CDIM * 96 * 96;

    f32x4 acc[4][4];
#pragma unroll
    for (int m = 0; m < 4; ++m)
#pragma unroll
        for (int n = 0; n < 4; ++n)
            acc[m][n] = (f32x4){0.f, 0.f, 0.f, 0.f};

    for (int k0 = 0; k0 < 1024; k0 += 64) {
        int c0 = k0 >> 2;               // 16 channels per K-block
        // B staging (bf16 weights, row-major k)
#pragma unroll
        for (int r = 0; r < 4; ++r) {
            int chunk = tid + 256 * r;
            int row = chunk >> 3;
            int kc = (chunk & 7) * 8;
            uint4 bv = *reinterpret_cast<const uint4*>(Bw + (size_t)(n0 + row) * 1024 + k0 + kc);
            int byte = (row * 128 + kc * 2) ^ ((row & 7) << 4);
            *reinterpret_cast<uint4*>(reinterpret_cast<char*>(Bsm) + byte) = bv;
        }
        // A staging direct from x: thread = (p-pair, c-pair); float4 along W.
#pragma unroll
        for (int r = 0; r < 2; ++r) {
            int id = tid + 256 * r;     // 0..511
            int pp = id & 63;           // p-pair index (lane-fastest => coalesced)
            int cp = id >> 6;           // 0..7
            int p_local = pp * 2;
            int rr = rem0 + p_local;
            int i2 = rr / 48, j2 = rr % 48;   // j2 even, pair never straddles a row
            int c = c0 + cp * 2;
            const float* s0 = xb + ((size_t)c * 96 + 2 * i2) * 96 + 2 * j2;
            float4 va = *reinterpret_cast<const float4*>(s0);                 // c,   kh=0
            float4 vb = *reinterpret_cast<const float4*>(s0 + 96);            // c,   kh=1
            float4 vc = *reinterpret_cast<const float4*>(s0 + 96 * 96);       // c+1, kh=0
            float4 vd = *reinterpret_cast<const float4*>(s0 + 96 * 96 + 96);  // c+1, kh=1
            uint4 w0, w1;   // row p_local gets (x,y) = kw 0,1; row p_local+1 gets (z,w)
            w0.x = (unsigned)f2bf(va.x) | ((unsigned)f2bf(va.y) << 16);
            w0.y = (unsigned)f2bf(vb.x) | ((unsigned)f2bf(vb.y) << 16);
            w0.z = (unsigned)f2bf(vc.x) | ((unsigned)f2bf(vc.y) << 16);
            w0.w = (unsigned)f2bf(vd.x) | ((unsigned)f2bf(vd.y) << 16);
            w1.x = (unsigned)f2bf(va.z) | ((unsigned)f2bf(va.w) << 16);
            w1.y = (unsigned)f2bf(vb.z) | ((unsigned)f2bf(vb.w) << 16);
            w1.z = (unsigned)f2bf(vc.z) | ((unsigned)f2bf(vc.w) << 16);
            w1.w = (unsigned)f2bf(vd.z) | ((unsigned)f2bf(vd.w) << 16);
            int byte0 = (p_local * 128 + cp * 16) ^ ((p_local & 7) << 4);
            int byte1 = ((p_local + 1) * 128 + cp * 16) ^ (((p_local + 1) & 7) << 4);
            *reinterpret_cast<uint4*>(reinterpret_cast<char*>(Asm) + byte0) = w0;
            *reinterpret_cast<uint4*>(reinterpret_cast<char*>(Asm) + byte1) = w1;
        }
        __syncthreads();
#pragma unroll
        for (int kk = 0; kk < 2; ++kk) {
            short8v af[4], bf[4];
#pragma unroll
            for (int m = 0; m < 4; ++m) {
                int row = wr * 64 + m * 16 + (lane & 15);
                int byte = (row * 128 + kk * 64 + (lane >> 4) * 16) ^ ((row & 7) << 4);
                af[m] = *reinterpret_cast<const short8v*>(reinterpret_cast<char*>(Asm) + byte);
            }
#pragma unroll
            for (int n = 0; n < 4; ++n) {
                int row = wc * 64 + n * 16 + (lane & 15);
                int byte = (row * 128 + kk * 64 + (lane >> 4) * 16) ^ ((row & 7) << 4);
                bf[n] = *reinterpret_cast<const short8v*>(reinterpret_cast<char*>(Bsm) + byte);
            }
#pragma unroll
            for (int m = 0; m < 4; ++m)
#pragma unroll
                for (int n = 0; n < 4; ++n)
                    acc[m][n] = __builtin_amdgcn_mfma_f32_16x16x32_bf16(af[m], bf[n], acc[m][n], 0, 0, 0);
        }
        __syncthreads();
    }
#pragma unroll
    for (int m = 0; m < 4; ++m) {
        int row0 = m0 + wr * 64 + m * 16 + (lane >> 4) * 4;
#pragma unroll
        for (int n = 0; n < 4; ++n) {
            int col = n0 + wc * 64 + n * 16 + (lane & 15);
#pragma unroll
            for (int r = 0; r < 4; ++r)
                Cout[(size_t)(row0 + r) * CDIM + col] = acc[m][n][r];
        }
    }
}

// ---------------- bf16 MFMA GEMM: C[M,N] = A[M,K] * B[N,K]^T ----------------
// 128x128 tile, BK=64, 4 waves each owning 64x64 (4x4 frags of 16x16x32).
// STORE_MODE 0: fp32 row-major; 1: fp32 transposed [(b*256+n)*2304+l]; 2: bf16 row-major
template<int STORE_MODE>
__global__ __launch_bounds__(256)
void k_gemm_mfma(const unsigned short* __restrict__ A, int lda,
                 const unsigned short* __restrict__ Bw, int ldb,
                 void* __restrict__ Cout, int ldc,
                 int N, int K)
{
    __shared__ __align__(16) unsigned short Asm[128 * 64];
    __shared__ __align__(16) unsigned short Bsm[128 * 64];
    int m0 = blockIdx.x * 128;
    int n0 = blockIdx.y * 128;
    int tid = threadIdx.x;
    int lane = tid & 63;
    int wid = tid >> 6;
    int wr = wid >> 1, wc = wid & 1;

    f32x4 acc[4][4];
#pragma unroll
    for (int m = 0; m < 4; ++m)
#pragma unroll
        for (int n = 0; n < 4; ++n)
            acc[m][n] = (f32x4){0.f, 0.f, 0.f, 0.f};

    for (int k0 = 0; k0 < K; k0 += 64) {
#pragma unroll
        for (int c = 0; c < 4; ++c) {
            int chunk = tid + 256 * c;            // 0..1023
            int row = chunk >> 3;                 // 0..127
            int kc = (chunk & 7) * 8;             // bf16 col 0,8,..,56
            uint4 av = *reinterpret_cast<const uint4*>(A + (size_t)(m0 + row) * lda + k0 + kc);
            int byte = (row * 128 + kc * 2) ^ ((row & 7) << 4);
            *reinterpret_cast<uint4*>(reinterpret_cast<char*>(Asm) + byte) = av;
            int nrow = n0 + row;
            uint4 bv = make_uint4(0u, 0u, 0u, 0u);
            if (nrow < N) bv = *reinterpret_cast<const uint4*>(Bw + (size_t)nrow * ldb + k0 + kc);
            *reinterpret_cast<uint4*>(reinterpret_cast<char*>(Bsm) + byte) = bv;
        }
        __syncthreads();
#pragma unroll
        for (int kk = 0; kk < 2; ++kk) {
            short8v af[4], bf[4];
#pragma unroll
            for (int m = 0; m < 4; ++m) {
                int row = wr * 64 + m * 16 + (lane & 15);
                int byte = (row * 128 + kk * 64 + (lane >> 4) * 16) ^ ((row & 7) << 4);
                af[m] = *reinterpret_cast<const short8v*>(reinterpret_cast<char*>(Asm) + byte);
            }
#pragma unroll
            for (int n = 0; n < 4; ++n) {
                int row = wc * 64 + n * 16 + (lane & 15);
                int byte = (row * 128 + kk * 64 + (lane >> 4) * 16) ^ ((row & 7) << 4);
                bf[n] = *reinterpret_cast<const short8v*>(reinterpret_cast<char*>(Bsm) + byte);
            }
#pragma unroll
            for (int m = 0; m < 4; ++m)
#pragma unroll
                for (int n = 0; n < 4; ++n)
                    acc[m][n] = __builtin_amdgcn_mfma_f32_16x16x32_bf16(af[m], bf[n], acc[m][n], 0, 0, 0);
        }
        __syncthreads();
    }

#pragma unroll
    for (int m = 0; m < 4; ++m) {
        int row0 = m0 + wr * 64 + m * 16 + (lane >> 4) * 4;
#pragma unroll
        for (int n = 0; n < 4; ++n) {
            int col = n0 + wc * 64 + n * 16 + (lane & 15);
            if (col < N) {
                if (STORE_MODE == 0) {
                    float* C = (float*)Cout;
#pragma unroll
                    for (int r = 0; r < 4; ++r)
                        C[(size_t)(row0 + r) * ldc + col] = acc[m][n][r];
                } else if (STORE_MODE == 1) {
                    float* C = (float*)Cout;
                    int b = row0 / LDIM, l = row0 % LDIM;
                    float4 v = make_float4(acc[m][n][0], acc[m][n][1], acc[m][n][2], acc[m][n][3]);
                    *reinterpret_cast<float4*>(C + ((size_t)(b * CDIM + col)) * LDIM + l) = v;
                } else {
                    unsigned short* C = (unsigned short*)Cout;
#pragma unroll
                    for (int r = 0; r < 4; ++r)
                        C[(size_t)(row0 + r) * ldc + col] = f2bf(acc[m][n][r]);
                }
            }
        }
    }
}

// ---------------- double LayerNorm [P,256] fp32 -> bf16 ---------------------
__device__ __forceinline__ float block_sum256(float v, float* sm) {
#pragma unroll
    for (int m = 32; m; m >>= 1) v += __shfl_xor(v, m);
    __syncthreads();
    if ((threadIdx.x & 63) == 0) sm[threadIdx.x >> 6] = v;
    __syncthreads();
    return sm[0] + sm[1] + sm[2] + sm[3];
}

__global__ __launch_bounds__(256)
void k_ln2(const float* __restrict__ xs,
           const float* __restrict__ g1, const float* __restrict__ b1,
           const float* __restrict__ g2, const float* __restrict__ b2,
           unsigned short* __restrict__ xsb)
{
    __shared__ float sm[4];
    int p = blockIdx.x;
    int c = threadIdx.x;
    float v = xs[(size_t)p * CDIM + c];
    float mu = block_sum256(v, sm) * (1.f / CDIM);
    float dv = v - mu;
    float var = block_sum256(dv * dv, sm) * (1.f / CDIM);
    float y = dv * rsqrtf(var + 1e-5f) * g1[c] + b1[c];
    float mu2 = block_sum256(y, sm) * (1.f / CDIM);
    float dy = y - mu2;
    float var2 = block_sum256(dy * dy, sm) * (1.f / CDIM);
    float y2 = dy * rsqrtf(var2 + 1e-5f) * g2[c] + b2[c];
    xsb[(size_t)p * CDIM + c] = f2bf(y2);
}

// ---------------- causal depthwise conv1d + SiLU (bf16 in, bf16 out) --------
__global__ void k_conv1d(const unsigned short* __restrict__ xz, const float* __restrict__ wc,
                         const float* __restrict__ bc, unsigned short* __restrict__ xcb)
{
    int idx = blockIdx.x * 256 + threadIdx.x;       // over P*512
    int d = idx & 511;
    int p = idx >> 9;
    int b = p / LDIM, l = p % LDIM;
    float4 w = *reinterpret_cast<const float4*>(wc + d * 4);
    const unsigned short* base = xz + (size_t)(b * LDIM) * 1024 + d;
    float acc = bc[d];
    if (l >= 3) acc = fmaf(b2f(base[(size_t)(l - 3) * 1024]), w.x, acc);
    if (l >= 2) acc = fmaf(b2f(base[(size_t)(l - 2) * 1024]), w.y, acc);
    if (l >= 1) acc = fmaf(b2f(base[(size_t)(l - 1) * 1024]), w.z, acc);
    acc = fmaf(b2f(base[(size_t)l * 1024]), w.w, acc);
    float sig = 1.f / (1.f + __expf(-acc));
    xcb[(size_t)p * DI + d] = f2bf(acc * sig);
}

// ---------------- dt = softplus(dbc[:, :16] @ w_dt^T + b_dt) -> bf16 --------
__global__ void k_dt(const float* __restrict__ dbc, const float* __restrict__ wdt,
                     const float* __restrict__ bdt, unsigned short* __restrict__ dtout)
{
    int idx = blockIdx.x * 256 + threadIdx.x;       // over P*512
    int d = idx & 511;
    int p = idx >> 9;
    const float* r = dbc + (size_t)p * HH;
    const float* w = wdt + d * 16;
    float acc = bdt[d];
#pragma unroll
    for (int k = 0; k < 16; ++k) acc = fmaf(r[k], w[k], acc);
    float sp = fmaxf(acc, 0.f) + log1pf(__expf(-fabsf(acc)));
    dtout[(size_t)p * 1024 + d] = f2bf(sp);
}

// ---------------- segmented selective scan ----------------------------------
__global__ __launch_bounds__(256)
void k_scan_p1(const unsigned short* __restrict__ xz,   // dt bf16 at [p*1024+d]
               const float* __restrict__ dbc,           // B at [p*48+16+s]
               const float* __restrict__ Alog,
               const unsigned short* __restrict__ xc,   // bf16
               float* __restrict__ aprod, float* __restrict__ hout)
{
    int t = blockIdx.x * 256 + threadIdx.x;        // 262144
    int d = t & 511;
    int rest = t >> 9;
    int b = rest / NSEG, seg = rest % NSEG;
    int l0 = seg * SEGLEN;
    float A[16], h[16], ap[16];
#pragma unroll
    for (int i = 0; i < 4; ++i) {
        float4 v = *reinterpret_cast<const float4*>(Alog + d * 16 + i * 4);
        A[4*i+0] = -__expf(v.x); A[4*i+1] = -__expf(v.y);
        A[4*i+2] = -__expf(v.z); A[4*i+3] = -__expf(v.w);
    }
#pragma unroll
    for (int s = 0; s < 16; ++s) { h[s] = 0.f; ap[s] = 1.f; }
    const unsigned short* dtp = xz + (size_t)(b * LDIM) * 1024;
    const unsigned short* xcp = xc + (size_t)(b * LDIM) * DI;
    const float* dbcb = dbc + (size_t)(b * LDIM) * HH;
    for (int i = 0; i < SEGLEN; ++i) {
        int l = l0 + i;
        float dt = b2f(dtp[(size_t)l * 1024 + d]);
        float xv = b2f(xcp[(size_t)l * DI + d]);
        float4 B0 = *reinterpret_cast<const float4*>(dbcb + l * HH + 16);
        float4 B1 = *reinterpret_cast<const float4*>(dbcb + l * HH + 20);
        float4 B2 = *reinterpret_cast<const float4*>(dbcb + l * HH + 24);
        float4 B3 = *reinterpret_cast<const float4*>(dbcb + l * HH + 28);
        float Bv[16] = {B0.x,B0.y,B0.z,B0.w, B1.x,B1.y,B1.z,B1.w,
                        B2.x,B2.y,B2.z,B2.w, B3.x,B3.y,B3.z,B3.w};
        float dtx = dt * xv;
#pragma unroll
        for (int s = 0; s < 16; ++s) {
            float dA = __expf(dt * A[s]);
            h[s] = fmaf(dA, h[s], dtx * Bv[s]);
            ap[s] *= dA;
        }
    }
    size_t base = ((size_t)((b * DI + d) * NSEG) + seg) * 16;
    float4* apo = reinterpret_cast<float4*>(aprod + base);
    float4* hoo = reinterpret_cast<float4*>(hout + base);
#pragma unroll
    for (int i = 0; i < 4; ++i) {
        apo[i] = make_float4(ap[4*i], ap[4*i+1], ap[4*i+2], ap[4*i+3]);
        hoo[i] = make_float4(h[4*i],  h[4*i+1],  h[4*i+2],  h[4*i+3]);
    }
}

__global__ __launch_bounds__(256)
void k_scan_p2(float* __restrict__ aprod, const float* __restrict__ hout)
{
    int t = blockIdx.x * 256 + threadIdx.x;        // 65536
    int s = t & 15;
    int g = t >> 4;
    float h = 0.f;
    for (int seg = 0; seg < NSEG; ++seg) {
        size_t idx = ((size_t)g * NSEG + seg) * 16 + s;
        float a  = aprod[idx];
        float ho = hout[idx];
        aprod[idx] = h;
        h = fmaf(a, h, ho);
    }
}

__global__ __launch_bounds__(256)
void k_scan_p3(const unsigned short* __restrict__ xz,   // dt bf16, z bf16 at +512
               const float* __restrict__ dbc,
               const float* __restrict__ Alog,
               const float* __restrict__ Dp,
               const float* __restrict__ hinit,
               unsigned short* __restrict__ xc_y)       // in: xc bf16; out: y bf16 in place
{
    int t = blockIdx.x * 256 + threadIdx.x;
    int d = t & 511;
    int rest = t >> 9;
    int b = rest / NSEG, seg = rest % NSEG;
    int l0 = seg * SEGLEN;
    float A[16], h[16];
#pragma unroll
    for (int i = 0; i < 4; ++i) {
        float4 v = *reinterpret_cast<const float4*>(Alog + d * 16 + i * 4);
        A[4*i+0] = -__expf(v.x); A[4*i+1] = -__expf(v.y);
        A[4*i+2] = -__expf(v.z); A[4*i+3] = -__expf(v.w);
    }
    size_t base = ((size_t)((b * DI + d) * NSEG) + seg) * 16;
#pragma unroll
    for (int i = 0; i < 4; ++i) {
        float4 v = *reinterpret_cast<const float4*>(hinit + base + 4 * i);
        h[4*i+0] = v.x; h[4*i+1] = v.y; h[4*i+2] = v.z; h[4*i+3] = v.w;
    }
    float Dv = Dp[d];
    const unsigned short* dtp = xz + (size_t)(b * LDIM) * 1024;
    const float* dbcb = dbc + (size_t)(b * LDIM) * HH;
    unsigned short* xcb = xc_y + (size_t)(b * LDIM) * DI;
    for (int i = 0; i < SEGLEN; ++i) {
        int l = l0 + i;
        float dt = b2f(dtp[(size_t)l * 1024 + d]);
        float zv = b2f(dtp[(size_t)l * 1024 + 512 + d]);
        float xv = b2f(xcb[(size_t)l * DI + d]);
        float4 B0 = *reinterpret_cast<const float4*>(dbcb + l * HH + 16);
        float4 B1 = *reinterpret_cast<const float4*>(dbcb + l * HH + 20);
        float4 B2 = *reinterpret_cast<const float4*>(dbcb + l * HH + 24);
        float4 B3 = *reinterpret_cast<const float4*>(dbcb + l * HH + 28);
        float4 C0 = *reinterpret_cast<const float4*>(dbcb + l * HH + 32);
        float4 C1 = *reinterpret_cast<const float4*>(dbcb + l * HH + 36);
        float4 C2 = *reinterpret_cast<const float4*>(dbcb + l * HH + 40);
        float4 C3 = *reinterpret_cast<const float4*>(dbcb + l * HH + 44);
        float Bv[16] = {B0.x,B0.y,B0.z,B0.w, B1.x,B1.y,B1.z,B1.w,
                        B2.x,B2.y,B2.z,B2.w, B3.x,B3.y,B3.z,B3.w};
        float Cv[16] = {C0.x,C0.y,C0.z,C0.w, C1.x,C1.y,C1.z,C1.w,
                        C2.x,C2.y,C2.z,C2.w, C3.x,C3.y,C3.z,C3.w};
        float dtx = dt * xv;
        float y = 0.f;
#pragma unroll
        for (int s = 0; s < 16; ++s) {
            float dA = __expf(dt * A[s]);
            h[s] = fmaf(dA, h[s], dtx * Bv[s]);
            y = fmaf(h[s], Cv[s], y);
        }
        y = fmaf(xv, Dv, y);
        float sig = 1.f / (1.f + __expf(-zv));
        xcb[(size_t)l * DI + d] = f2bf(y * (zv * sig));
    }
}

extern "C" void kernel_launch(void* const* d_in, const int* in_sizes, int n_in,
                              void* d_out, int out_size, void* d_ws, size_t ws_size,
                              hipStream_t stream) {
    const float* x      = (const float*)d_in[0];
    const float* w_down = (const float*)d_in[1];
    const float* g1     = (const float*)d_in[2];
    const float* b1     = (const float*)d_in[3];
    const float* g2     = (const float*)d_in[4];
    const float* b2     = (const float*)d_in[5];
    const float* w_in   = (const float*)d_in[6];
    const float* w_conv = (const float*)d_in[7];
    const float* b_conv = (const float*)d_in[8];
    const float* w_xprj = (const float*)d_in[9];
    const float* w_dt   = (const float*)d_in[10];
    const float* b_dt   = (const float*)d_in[11];
    const float* A_log  = (const float*)d_in[12];
    const float* Dp     = (const float*)d_in[13];
    const float* w_out  = (const float*)d_in[14];
    float* out = (float*)d_out;

    // ws layout (bytes from base), total ~101 MB < 113.25 MB proven budget:
    char* wsb = (char*)d_ws;
    unsigned short* R0  = (unsigned short*)wsb;                      // [P,1024] bf16: xz (dt in xm half)
    unsigned short* R1  = (unsigned short*)(wsb + 37748736);         // [P,256]  bf16: xs
    unsigned short* R3  = (unsigned short*)(wsb + 47185920);         // [P,512]  bf16: xc -> y (in place)
    float*          aprod = (float*)(wsb + 66060288);                // 4.19M floats (16.78 MB)
    float*          hout  = (float*)(wsb + 82837504);                // 4.19M floats (16.78 MB)
    unsigned short* Wb  = (unsigned short*)(wsb + 99614720);         // weights bf16 (1.36 MB)
    unsigned short* wdownb = Wb;                                     // 262144
    unsigned short* winb   = Wb + 262144;                            // 262144
    unsigned short* wxb    = Wb + 524288;                            // 24576
    unsigned short* woutb  = Wb + 548864;                            // 131072

    // 0. weight casts
    k_cast<<<1024, 256, 0, stream>>>(w_down, wdownb, 262144);
    k_cast<<<1024, 256, 0, stream>>>(w_in,   winb,   262144);
    k_cast<<<96,   256, 0, stream>>>(w_xprj, wxb,    24576);
    k_cast<<<512,  256, 0, stream>>>(w_out,  woutb,  131072);
    // 1+2. fused im2col + down-proj GEMM -> xd in d_out fp32 [P,256]
    k_gemm_down<<<dim3(144, 2), 256, 0, stream>>>(x, wdownb, out);
    // 3. double LayerNorm -> xs bf16 (R1)
    k_ln2<<<PDIM, 256, 0, stream>>>(out, g1, b1, g2, b2, R1);
    // 4. xz = xs @ w_in^T -> R0 bf16 [P,1024]
    k_gemm_mfma<2><<<dim3(144, 8), 256, 0, stream>>>(R1, 256, winb, 256, R0, 1024, 1024, 256);
    // 5. conv1d + SiLU -> xc bf16 (R3)
    k_conv1d<<<PDIM * DI / 256, 256, 0, stream>>>(R0, w_conv, b_conv, R3);
    // 6. dbc = xc @ w_xproj^T -> d_out fp32 [P,48]
    k_gemm_mfma<0><<<dim3(144, 1), 256, 0, stream>>>(R3, 512, wxb, 512, out, HH, HH, 512);
    // 7. dt = softplus(...) -> bf16 into xm half of R0
    k_dt<<<PDIM * DI / 256, 256, 0, stream>>>(out, w_dt, b_dt, R0);
    // 8. segmented scan + gating -> y bf16 in place over R3
    k_scan_p1<<<BDIM * NSEG * DI / 256, 256, 0, stream>>>(R0, out, A_log, R3, aprod, hout);
    k_scan_p2<<<BDIM * DI * 16 / 256, 256, 0, stream>>>(aprod, hout);
    k_scan_p3<<<BDIM * NSEG * DI / 256, 256, 0, stream>>>(R0, out, A_log, Dp, aprod, R3);
    // 9. out = y @ w_out^T, transposed store to [B,C,48,48]
    k_gemm_mfma<1><<<dim3(144, 2), 256, 0, stream>>>(R3, 512, woutb, 512, out, 0, 256, 512);
}

// Round 6
// 296.190 us; speedup vs baseline: 8.1439x; 1.1354x over previous
//
#include <hip/hip_runtime.h>
#include <math.h>

#define PDIM 18432      // B*L
#define LDIM 2304
#define BDIM 8
#define CDIM 256
#define DI   512
#define DS   16

#define NSEG 64
#define SEGLEN 36       // LDIM / NSEG

typedef short short8v __attribute__((ext_vector_type(8)));
typedef float f32x4 __attribute__((ext_vector_type(4)));

__device__ __forceinline__ unsigned short f2bf(float f) {
    unsigned u = __float_as_uint(f);
    unsigned r = (u + 0x7fff + ((u >> 16) & 1)) >> 16;
    return (unsigned short)r;
}
__device__ __forceinline__ float b2f(unsigned short u) {
    return __uint_as_float(((unsigned)u) << 16);
}

// ---------------- weight prep: bf16 casts + combined dt weight --------------
// bw2[544][512]: rows 0..31 = w_xproj rows 16..47 (B,C); rows 32..543 =
// W_comb[d][k] = sum_j w_dt[d][j] * w_xproj[j][k]
__global__ void k_prep(const float* __restrict__ wdown, const float* __restrict__ win,
                       const float* __restrict__ wout, const float* __restrict__ wx,
                       const float* __restrict__ wdt,
                       unsigned short* __restrict__ wdownb, unsigned short* __restrict__ winb,
                       unsigned short* __restrict__ woutb, unsigned short* __restrict__ bw2)
{
    int i = blockIdx.x * 256 + threadIdx.x;
    if (i < 262144) { wdownb[i] = f2bf(wdown[i]); return; }
    i -= 262144;
    if (i < 262144) { winb[i] = f2bf(win[i]); return; }
    i -= 262144;
    if (i < 131072) { woutb[i] = f2bf(wout[i]); return; }
    i -= 131072;
    if (i >= 278528) return;
    int n = i >> 9, k = i & 511;
    float v;
    if (n < 32) {
        v = wx[(size_t)(16 + n) * 512 + k];
    } else {
        const float* wd = wdt + (size_t)(n - 32) * 16;
        v = 0.f;
#pragma unroll
        for (int j = 0; j < 16; ++j) v = fmaf(wd[j], wx[(size_t)j * 512 + k], v);
    }
    bw2[i] = f2bf(v);
}

// ---------------- fused im2col + down-proj GEMM -----------------------------
__global__ __launch_bounds__(256)
void k_gemm_down(const float* __restrict__ X,
                 const unsigned short* __restrict__ Bw,
                 float* __restrict__ Cout)
{
    __shared__ __align__(16) unsigned short Asm[128 * 64];
    __shared__ __align__(16) unsigned short Bsm[128 * 64];
    int m0 = blockIdx.x * 128;
    int n0 = blockIdx.y * 128;
    int tid = threadIdx.x;
    int lane = tid & 63;
    int wid = tid >> 6;
    int wr = wid >> 1, wc = wid & 1;
    int bb = m0 / LDIM;
    int rem0 = m0 % LDIM;
    const float* xb = X + (size_t)bb * CDIM * 96 * 96;

    f32x4 acc[4][4];
#pragma unroll
    for (int m = 0; m < 4; ++m)
#pragma unroll
        for (int n = 0; n < 4; ++n)
            acc[m][n] = (f32x4){0.f, 0.f, 0.f, 0.f};

    for (int k0 = 0; k0 < 1024; k0 += 64) {
        int c0 = k0 >> 2;
#pragma unroll
        for (int r = 0; r < 4; ++r) {
            int chunk = tid + 256 * r;
            int row = chunk >> 3;
            int kc = (chunk & 7) * 8;
            uint4 bv = *reinterpret_cast<const uint4*>(Bw + (size_t)(n0 + row) * 1024 + k0 + kc);
            int byte = (row * 128 + kc * 2) ^ ((row & 7) << 4);
            *reinterpret_cast<uint4*>(reinterpret_cast<char*>(Bsm) + byte) = bv;
        }
#pragma unroll
        for (int r = 0; r < 2; ++r) {
            int id = tid + 256 * r;
            int pp = id & 63;
            int cp = id >> 6;
            int p_local = pp * 2;
            int rr = rem0 + p_local;
            int i2 = rr / 48, j2 = rr % 48;
            int c = c0 + cp * 2;
            const float* s0 = xb + ((size_t)c * 96 + 2 * i2) * 96 + 2 * j2;
            float4 va = *reinterpret_cast<const float4*>(s0);
            float4 vb = *reinterpret_cast<const float4*>(s0 + 96);
            float4 vc = *reinterpret_cast<const float4*>(s0 + 96 * 96);
            float4 vd = *reinterpret_cast<const float4*>(s0 + 96 * 96 + 96);
            uint4 w0, w1;
            w0.x = (unsigned)f2bf(va.x) | ((unsigned)f2bf(va.y) << 16);
            w0.y = (unsigned)f2bf(vb.x) | ((unsigned)f2bf(vb.y) << 16);
            w0.z = (unsigned)f2bf(vc.x) | ((unsigned)f2bf(vc.y) << 16);
            w0.w = (unsigned)f2bf(vd.x) | ((unsigned)f2bf(vd.y) << 16);
            w1.x = (unsigned)f2bf(va.z) | ((unsigned)f2bf(va.w) << 16);
            w1.y = (unsigned)f2bf(vb.z) | ((unsigned)f2bf(vb.w) << 16);
            w1.z = (unsigned)f2bf(vc.z) | ((unsigned)f2bf(vc.w) << 16);
            w1.w = (unsigned)f2bf(vd.z) | ((unsigned)f2bf(vd.w) << 16);
            int byte0 = (p_local * 128 + cp * 16) ^ ((p_local & 7) << 4);
            int byte1 = ((p_local + 1) * 128 + cp * 16) ^ (((p_local + 1) & 7) << 4);
            *reinterpret_cast<uint4*>(reinterpret_cast<char*>(Asm) + byte0) = w0;
            *reinterpret_cast<uint4*>(reinterpret_cast<char*>(Asm) + byte1) = w1;
        }
        __syncthreads();
#pragma unroll
        for (int kk = 0; kk < 2; ++kk) {
            short8v af[4], bf[4];
#pragma unroll
            for (int m = 0; m < 4; ++m) {
                int row = wr * 64 + m * 16 + (lane & 15);
                int byte = (row * 128 + kk * 64 + (lane >> 4) * 16) ^ ((row & 7) << 4);
                af[m] = *reinterpret_cast<const short8v*>(reinterpret_cast<char*>(Asm) + byte);
            }
#pragma unroll
            for (int n = 0; n < 4; ++n) {
                int row = wc * 64 + n * 16 + (lane & 15);
                int byte = (row * 128 + kk * 64 + (lane >> 4) * 16) ^ ((row & 7) << 4);
                bf[n] = *reinterpret_cast<const short8v*>(reinterpret_cast<char*>(Bsm) + byte);
            }
#pragma unroll
            for (int m = 0; m < 4; ++m)
#pragma unroll
                for (int n = 0; n < 4; ++n)
                    acc[m][n] = __builtin_amdgcn_mfma_f32_16x16x32_bf16(af[m], bf[n], acc[m][n], 0, 0, 0);
        }
        __syncthreads();
    }
#pragma unroll
    for (int m = 0; m < 4; ++m) {
        int row0 = m0 + wr * 64 + m * 16 + (lane >> 4) * 4;
#pragma unroll
        for (int n = 0; n < 4; ++n) {
            int col = n0 + wc * 64 + n * 16 + (lane & 15);
#pragma unroll
            for (int r = 0; r < 4; ++r)
                Cout[(size_t)(row0 + r) * CDIM + col] = acc[m][n][r];
        }
    }
}

// ---------------- bf16 MFMA GEMM: C[M,N] = A[M,K] * B[N,K]^T ----------------
// STORE_MODE 1: fp32 transposed [(b*256+n)*2304+l]; 2: bf16 row-major
template<int STORE_MODE>
__global__ __launch_bounds__(256)
void k_gemm_mfma(const unsigned short* __restrict__ A, int lda,
                 const unsigned short* __restrict__ Bw, int ldb,
                 void* __restrict__ Cout, int ldc,
                 int N, int K)
{
    __shared__ __align__(16) unsigned short Asm[128 * 64];
    __shared__ __align__(16) unsigned short Bsm[128 * 64];
    int m0 = blockIdx.x * 128;
    int n0 = blockIdx.y * 128;
    int tid = threadIdx.x;
    int lane = tid & 63;
    int wid = tid >> 6;
    int wr = wid >> 1, wc = wid & 1;

    f32x4 acc[4][4];
#pragma unroll
    for (int m = 0; m < 4; ++m)
#pragma unroll
        for (int n = 0; n < 4; ++n)
            acc[m][n] = (f32x4){0.f, 0.f, 0.f, 0.f};

    for (int k0 = 0; k0 < K; k0 += 64) {
#pragma unroll
        for (int c = 0; c < 4; ++c) {
            int chunk = tid + 256 * c;
            int row = chunk >> 3;
            int kc = (chunk & 7) * 8;
            uint4 av = *reinterpret_cast<const uint4*>(A + (size_t)(m0 + row) * lda + k0 + kc);
            int byte = (row * 128 + kc * 2) ^ ((row & 7) << 4);
            *reinterpret_cast<uint4*>(reinterpret_cast<char*>(Asm) + byte) = av;
            int nrow = n0 + row;
            uint4 bv = make_uint4(0u, 0u, 0u, 0u);
            if (nrow < N) bv = *reinterpret_cast<const uint4*>(Bw + (size_t)nrow * ldb + k0 + kc);
            *reinterpret_cast<uint4*>(reinterpret_cast<char*>(Bsm) + byte) = bv;
        }
        __syncthreads();
#pragma unroll
        for (int kk = 0; kk < 2; ++kk) {
            short8v af[4], bf[4];
#pragma unroll
            for (int m = 0; m < 4; ++m) {
                int row = wr * 64 + m * 16 + (lane & 15);
                int byte = (row * 128 + kk * 64 + (lane >> 4) * 16) ^ ((row & 7) << 4);
                af[m] = *reinterpret_cast<const short8v*>(reinterpret_cast<char*>(Asm) + byte);
            }
#pragma unroll
            for (int n = 0; n < 4; ++n) {
                int row = wc * 64 + n * 16 + (lane & 15);
                int byte = (row * 128 + kk * 64 + (lane >> 4) * 16) ^ ((row & 7) << 4);
                bf[n] = *reinterpret_cast<const short8v*>(reinterpret_cast<char*>(Bsm) + byte);
            }
#pragma unroll
            for (int m = 0; m < 4; ++m)
#pragma unroll
                for (int n = 0; n < 4; ++n)
                    acc[m][n] = __builtin_amdgcn_mfma_f32_16x16x32_bf16(af[m], bf[n], acc[m][n], 0, 0, 0);
        }
        __syncthreads();
    }

#pragma unroll
    for (int m = 0; m < 4; ++m) {
        int row0 = m0 + wr * 64 + m * 16 + (lane >> 4) * 4;
#pragma unroll
        for (int n = 0; n < 4; ++n) {
            int col = n0 + wc * 64 + n * 16 + (lane & 15);
            if (col < N) {
                if (STORE_MODE == 1) {
                    float* C = (float*)Cout;
                    int b = row0 / LDIM, l = row0 % LDIM;
                    float4 v = make_float4(acc[m][n][0], acc[m][n][1], acc[m][n][2], acc[m][n][3]);
                    *reinterpret_cast<float4*>(C + ((size_t)(b * CDIM + col)) * LDIM + l) = v;
                } else {
                    unsigned short* C = (unsigned short*)Cout;
#pragma unroll
                    for (int r = 0; r < 4; ++r)
                        C[(size_t)(row0 + r) * ldc + col] = f2bf(acc[m][n][r]);
                }
            }
        }
    }
}

// ---------------- fused x_proj + dt GEMM ------------------------------------
// A = xc bf16 [P,512]; Bw2 [544,512]: 0..31 -> dbc32 fp32 [P,32];
// 32..543 -> dt = softplus(v + b_dt) bf16 into xz xm slots [p*1024 + d]
__global__ __launch_bounds__(256)
void k_gemm_xdt(const unsigned short* __restrict__ A,
                const unsigned short* __restrict__ Bw,
                const float* __restrict__ bdt,
                float* __restrict__ dbc32,
                unsigned short* __restrict__ dtout)
{
    __shared__ __align__(16) unsigned short Asm[128 * 64];
    __shared__ __align__(16) unsigned short Bsm[128 * 64];
    int m0 = blockIdx.x * 128;
    int n0 = blockIdx.y * 128;
    int tid = threadIdx.x;
    int lane = tid & 63;
    int wid = tid >> 6;
    int wr = wid >> 1, wc = wid & 1;

    f32x4 acc[4][4];
#pragma unroll
    for (int m = 0; m < 4; ++m)
#pragma unroll
        for (int n = 0; n < 4; ++n)
            acc[m][n] = (f32x4){0.f, 0.f, 0.f, 0.f};

    for (int k0 = 0; k0 < 512; k0 += 64) {
#pragma unroll
        for (int c = 0; c < 4; ++c) {
            int chunk = tid + 256 * c;
            int row = chunk >> 3;
            int kc = (chunk & 7) * 8;
            uint4 av = *reinterpret_cast<const uint4*>(A + (size_t)(m0 + row) * 512 + k0 + kc);
            int byte = (row * 128 + kc * 2) ^ ((row & 7) << 4);
            *reinterpret_cast<uint4*>(reinterpret_cast<char*>(Asm) + byte) = av;
            int nrow = n0 + row;
            uint4 bv = make_uint4(0u, 0u, 0u, 0u);
            if (nrow < 544) bv = *reinterpret_cast<const uint4*>(Bw + (size_t)nrow * 512 + k0 + kc);
            *reinterpret_cast<uint4*>(reinterpret_cast<char*>(Bsm) + byte) = bv;
        }
        __syncthreads();
#pragma unroll
        for (int kk = 0; kk < 2; ++kk) {
            short8v af[4], bf[4];
#pragma unroll
            for (int m = 0; m < 4; ++m) {
                int row = wr * 64 + m * 16 + (lane & 15);
                int byte = (row * 128 + kk * 64 + (lane >> 4) * 16) ^ ((row & 7) << 4);
                af[m] = *reinterpret_cast<const short8v*>(reinterpret_cast<char*>(Asm) + byte);
            }
#pragma unroll
            for (int n = 0; n < 4; ++n) {
                int row = wc * 64 + n * 16 + (lane & 15);
                int byte = (row * 128 + kk * 64 + (lane >> 4) * 16) ^ ((row & 7) << 4);
                bf[n] = *reinterpret_cast<const short8v*>(reinterpret_cast<char*>(Bsm) + byte);
            }
#pragma unroll
            for (int m = 0; m < 4; ++m)
#pragma unroll
                for (int n = 0; n < 4; ++n)
                    acc[m][n] = __builtin_amdgcn_mfma_f32_16x16x32_bf16(af[m], bf[n], acc[m][n], 0, 0, 0);
        }
        __syncthreads();
    }

#pragma unroll
    for (int m = 0; m < 4; ++m) {
        int row0 = m0 + wr * 64 + m * 16 + (lane >> 4) * 4;
#pragma unroll
        for (int n = 0; n < 4; ++n) {
            int col = n0 + wc * 64 + n * 16 + (lane & 15);
            if (col < 32) {
#pragma unroll
                for (int r = 0; r < 4; ++r)
                    dbc32[(size_t)(row0 + r) * 32 + col] = acc[m][n][r];
            } else if (col < 544) {
                int d = col - 32;
                float bd = bdt[d];
#pragma unroll
                for (int r = 0; r < 4; ++r) {
                    float v = acc[m][n][r] + bd;
                    float sp = fmaxf(v, 0.f) + __logf(1.f + __expf(-fabsf(v)));
                    dtout[(size_t)(row0 + r) * 1024 + d] = f2bf(sp);
                }
            }
        }
    }
}

// ---------------- double LayerNorm [P,256] fp32 -> bf16 ---------------------
__device__ __forceinline__ float block_sum256(float v, float* sm) {
#pragma unroll
    for (int m = 32; m; m >>= 1) v += __shfl_xor(v, m);
    __syncthreads();
    if ((threadIdx.x & 63) == 0) sm[threadIdx.x >> 6] = v;
    __syncthreads();
    return sm[0] + sm[1] + sm[2] + sm[3];
}

__global__ __launch_bounds__(256)
void k_ln2(const float* __restrict__ xs,
           const float* __restrict__ g1, const float* __restrict__ b1,
           const float* __restrict__ g2, const float* __restrict__ b2,
           unsigned short* __restrict__ xsb)
{
    __shared__ float sm[4];
    int p = blockIdx.x;
    int c = threadIdx.x;
    float v = xs[(size_t)p * CDIM + c];
    float mu = block_sum256(v, sm) * (1.f / CDIM);
    float dv = v - mu;
    float var = block_sum256(dv * dv, sm) * (1.f / CDIM);
    float y = dv * rsqrtf(var + 1e-5f) * g1[c] + b1[c];
    float mu2 = block_sum256(y, sm) * (1.f / CDIM);
    float dy = y - mu2;
    float var2 = block_sum256(dy * dy, sm) * (1.f / CDIM);
    float y2 = dy * rsqrtf(var2 + 1e-5f) * g2[c] + b2[c];
    xsb[(size_t)p * CDIM + c] = f2bf(y2);
}

// ---------------- causal depthwise conv1d + SiLU (bf16 in, bf16 out) --------
__global__ void k_conv1d(const unsigned short* __restrict__ xz, const float* __restrict__ wc,
                         const float* __restrict__ bc, unsigned short* __restrict__ xcb)
{
    int idx = blockIdx.x * 256 + threadIdx.x;       // over P*512
    int d = idx & 511;
    int p = idx >> 9;
    int b = p / LDIM, l = p % LDIM;
    float4 w = *reinterpret_cast<const float4*>(wc + d * 4);
    const unsigned short* base = xz + (size_t)(b * LDIM) * 1024 + d;
    float acc = bc[d];
    if (l >= 3) acc = fmaf(b2f(base[(size_t)(l - 3) * 1024]), w.x, acc);
    if (l >= 2) acc = fmaf(b2f(base[(size_t)(l - 2) * 1024]), w.y, acc);
    if (l >= 1) acc = fmaf(b2f(base[(size_t)(l - 1) * 1024]), w.z, acc);
    acc = fmaf(b2f(base[(size_t)l * 1024]), w.w, acc);
    float sig = 1.f / (1.f + __expf(-acc));
    xcb[(size_t)p * DI + d] = f2bf(acc * sig);
}

// ---------------- segmented selective scan ----------------------------------
__global__ __launch_bounds__(256)
void k_scan_p1(const unsigned short* __restrict__ xz,   // dt bf16 at [p*1024+d]
               const float* __restrict__ dbc,           // [P,32]: B s, C s+16
               const float* __restrict__ Alog,
               const unsigned short* __restrict__ xc,   // bf16
               float* __restrict__ aprod, float* __restrict__ hout)
{
    int t = blockIdx.x * 256 + threadIdx.x;        // 262144
    int d = t & 511;
    int rest = t >> 9;
    int b = rest / NSEG, seg = rest % NSEG;
    int l0 = seg * SEGLEN;
    float A[16], h[16], ap[16];
#pragma unroll
    for (int i = 0; i < 4; ++i) {
        float4 v = *reinterpret_cast<const float4*>(Alog + d * 16 + i * 4);
        A[4*i+0] = -__expf(v.x); A[4*i+1] = -__expf(v.y);
        A[4*i+2] = -__expf(v.z); A[4*i+3] = -__expf(v.w);
    }
#pragma unroll
    for (int s = 0; s < 16; ++s) { h[s] = 0.f; ap[s] = 1.f; }
    const unsigned short* dtp = xz + (size_t)(b * LDIM) * 1024;
    const unsigned short* xcp = xc + (size_t)(b * LDIM) * DI;
    const float* dbcb = dbc + (size_t)(b * LDIM) * 32;
    for (int i = 0; i < SEGLEN; ++i) {
        int l = l0 + i;
        float dt = b2f(dtp[(size_t)l * 1024 + d]);
        float xv = b2f(xcp[(size_t)l * DI + d]);
        float4 B0 = *reinterpret_cast<const float4*>(dbcb + l * 32 + 0);
        float4 B1 = *reinterpret_cast<const float4*>(dbcb + l * 32 + 4);
        float4 B2 = *reinterpret_cast<const float4*>(dbcb + l * 32 + 8);
        float4 B3 = *reinterpret_cast<const float4*>(dbcb + l * 32 + 12);
        float Bv[16] = {B0.x,B0.y,B0.z,B0.w, B1.x,B1.y,B1.z,B1.w,
                        B2.x,B2.y,B2.z,B2.w, B3.x,B3.y,B3.z,B3.w};
        float dtx = dt * xv;
#pragma unroll
        for (int s = 0; s < 16; ++s) {
            float dA = __expf(dt * A[s]);
            h[s] = fmaf(dA, h[s], dtx * Bv[s]);
            ap[s] *= dA;
        }
    }
    size_t base = ((size_t)((b * DI + d) * NSEG) + seg) * 16;
    float4* apo = reinterpret_cast<float4*>(aprod + base);
    float4* hoo = reinterpret_cast<float4*>(hout + base);
#pragma unroll
    for (int i = 0; i < 4; ++i) {
        apo[i] = make_float4(ap[4*i], ap[4*i+1], ap[4*i+2], ap[4*i+3]);
        hoo[i] = make_float4(h[4*i],  h[4*i+1],  h[4*i+2],  h[4*i+3]);
    }
}

__global__ __launch_bounds__(256)
void k_scan_p2(float* __restrict__ aprod, const float* __restrict__ hout)
{
    int t = blockIdx.x * 256 + threadIdx.x;        // 65536
    int s = t & 15;
    int g = t >> 4;
    float h = 0.f;
    for (int seg = 0; seg < NSEG; ++seg) {
        size_t idx = ((size_t)g * NSEG + seg) * 16 + s;
        float a  = aprod[idx];
        float ho = hout[idx];
        aprod[idx] = h;
        h = fmaf(a, h, ho);
    }
}

__global__ __launch_bounds__(256)
void k_scan_p3(const unsigned short* __restrict__ xz,   // dt bf16, z bf16 at +512
               const float* __restrict__ dbc,           // [P,32]
               const float* __restrict__ Alog,
               const float* __restrict__ Dp,
               const float* __restrict__ hinit,
               unsigned short* __restrict__ xc_y)       // in: xc bf16; out: y bf16 in place
{
    int t = blockIdx.x * 256 + threadIdx.x;
    int d = t & 511;
    int rest = t >> 9;
    int b = rest / NSEG, seg = rest % NSEG;
    int l0 = seg * SEGLEN;
    float A[16], h[16];
#pragma unroll
    for (int i = 0; i < 4; ++i) {
        float4 v = *reinterpret_cast<const float4*>(Alog + d * 16 + i * 4);
        A[4*i+0] = -__expf(v.x); A[4*i+1] = -__expf(v.y);
        A[4*i+2] = -__expf(v.z); A[4*i+3] = -__expf(v.w);
    }
    size_t base = ((size_t)((b * DI + d) * NSEG) + seg) * 16;
#pragma unroll
    for (int i = 0; i < 4; ++i) {
        float4 v = *reinterpret_cast<const float4*>(hinit + base + 4 * i);
        h[4*i+0] = v.x; h[4*i+1] = v.y; h[4*i+2] = v.z; h[4*i+3] = v.w;
    }
    float Dv = Dp[d];
    const unsigned short* dtp = xz + (size_t)(b * LDIM) * 1024;
    const float* dbcb = dbc + (size_t)(b * LDIM) * 32;
    unsigned short* xcb = xc_y + (size_t)(b * LDIM) * DI;
    for (int i = 0; i < SEGLEN; ++i) {
        int l = l0 + i;
        float dt = b2f(dtp[(size_t)l * 1024 + d]);
        float zv = b2f(dtp[(size_t)l * 1024 + 512 + d]);
        float xv = b2f(xcb[(size_t)l * DI + d]);
        float4 B0 = *reinterpret_cast<const float4*>(dbcb + l * 32 + 0);
        float4 B1 = *reinterpret_cast<const float4*>(dbcb + l * 32 + 4);
        float4 B2 = *reinterpret_cast<const float4*>(dbcb + l * 32 + 8);
        float4 B3 = *reinterpret_cast<const float4*>(dbcb + l * 32 + 12);
        float4 C0 = *reinterpret_cast<const float4*>(dbcb + l * 32 + 16);
        float4 C1 = *reinterpret_cast<const float4*>(dbcb + l * 32 + 20);
        float4 C2 = *reinterpret_cast<const float4*>(dbcb + l * 32 + 24);
        float4 C3 = *reinterpret_cast<const float4*>(dbcb + l * 32 + 28);
        float Bv[16] = {B0.x,B0.y,B0.z,B0.w, B1.x,B1.y,B1.z,B1.w,
                        B2.x,B2.y,B2.z,B2.w, B3.x,B3.y,B3.z,B3.w};
        float Cv[16] = {C0.x,C0.y,C0.z,C0.w, C1.x,C1.y,C1.z,C1.w,
                        C2.x,C2.y,C2.z,C2.w, C3.x,C3.y,C3.z,C3.w};
        float dtx = dt * xv;
        float y = 0.f;
#pragma unroll
        for (int s = 0; s < 16; ++s) {
            float dA = __expf(dt * A[s]);
            h[s] = fmaf(dA, h[s], dtx * Bv[s]);
            y = fmaf(h[s], Cv[s], y);
        }
        y = fmaf(xv, Dv, y);
        float sig = 1.f / (1.f + __expf(-zv));
        xcb[(size_t)l * DI + d] = f2bf(y * (zv * sig));
    }
}

extern "C" void kernel_launch(void* const* d_in, const int* in_sizes, int n_in,
                              void* d_out, int out_size, void* d_ws, size_t ws_size,
                              hipStream_t stream) {
    const float* x      = (const float*)d_in[0];
    const float* w_down = (const float*)d_in[1];
    const float* g1     = (const float*)d_in[2];
    const float* b1     = (const float*)d_in[3];
    const float* g2     = (const float*)d_in[4];
    const float* b2     = (const float*)d_in[5];
    const float* w_in   = (const float*)d_in[6];
    const float* w_conv = (const float*)d_in[7];
    const float* b_conv = (const float*)d_in[8];
    const float* w_xprj = (const float*)d_in[9];
    const float* w_dt   = (const float*)d_in[10];
    const float* b_dt   = (const float*)d_in[11];
    const float* A_log  = (const float*)d_in[12];
    const float* Dp     = (const float*)d_in[13];
    const float* w_out  = (const float*)d_in[14];
    float* out = (float*)d_out;

    // ws layout (bytes from base), total ~101.5 MB:
    char* wsb = (char*)d_ws;
    unsigned short* R0  = (unsigned short*)wsb;                      // [P,1024] bf16: xz (dt in xm half)
    unsigned short* R1  = (unsigned short*)(wsb + 37748736);         // [P,256]  bf16: xs
    unsigned short* R3  = (unsigned short*)(wsb + 47185920);         // [P,512]  bf16: xc -> y (in place)
    float*          aprod = (float*)(wsb + 66060288);                // 16.78 MB
    float*          hout  = (float*)(wsb + 82837504);                // 16.78 MB
    unsigned short* Wb  = (unsigned short*)(wsb + 99614720);         // weights bf16 (1.87 MB)
    unsigned short* wdownb = Wb;                                     // 262144
    unsigned short* winb   = Wb + 262144;                            // 262144
    unsigned short* woutb  = Wb + 524288;                            // 131072
    unsigned short* bw2    = Wb + 655360;                            // 278528 (544x512)

    // dbc32 [P,32] fp32 lives in d_out (rewritten by final GEMM)
    float* dbc32 = out;

    // 0. weight prep (casts + combined dt weight), one launch
    k_prep<<<3648, 256, 0, stream>>>(w_down, w_in, w_out, w_xprj, w_dt,
                                     wdownb, winb, woutb, bw2);
    // 1. fused im2col + down-proj GEMM -> xd fp32, use tail of ws? no: d_out
    //    xd lives in d_out[P*32 .. P*32+P*256)? dbc32 written later; xd first.
    //    xd -> d_out (full [P,256]); LN consumes it before dbc32 overwrites.
    k_gemm_down<<<dim3(144, 2), 256, 0, stream>>>(x, wdownb, out);
    // 2. double LayerNorm -> xs bf16 (R1)
    k_ln2<<<PDIM, 256, 0, stream>>>(out, g1, b1, g2, b2, R1);
    // 3. xz = xs @ w_in^T -> R0 bf16 [P,1024]
    k_gemm_mfma<2><<<dim3(144, 8), 256, 0, stream>>>(R1, 256, winb, 256, R0, 1024, 1024, 256);
    // 4. conv1d + SiLU -> xc bf16 (R3)
    k_conv1d<<<PDIM * DI / 256, 256, 0, stream>>>(R0, w_conv, b_conv, R3);
    // 5. fused x_proj + dt GEMM -> dbc32 (d_out) + dt (R0 xm half)
    k_gemm_xdt<<<dim3(144, 5), 256, 0, stream>>>(R3, bw2, b_dt, dbc32, R0);
    // 6. segmented scan + gating -> y bf16 in place over R3
    k_scan_p1<<<BDIM * NSEG * DI / 256, 256, 0, stream>>>(R0, dbc32, A_log, R3, aprod, hout);
    k_scan_p2<<<BDIM * DI * 16 / 256, 256, 0, stream>>>(aprod, hout);
    k_scan_p3<<<BDIM * NSEG * DI / 256, 256, 0, stream>>>(R0, dbc32, A_log, Dp, aprod, R3);
    // 7. out = y @ w_out^T, transposed store to [B,C,48,48]
    k_gemm_mfma<1><<<dim3(144, 2), 256, 0, stream>>>(R3, 512, woutb, 512, out, 0, 256, 512);
}